// Round 3
// baseline (1776.649 us; speedup 1.0000x reference)
//
#include <hip/hip_runtime.h>
#include <math.h>

#define BT   4096
#define Cdim 1024
#define Hn   16
#define Nelem 64
#define Tn   1024

typedef unsigned short ushort_t;
typedef short bf16x8 __attribute__((ext_vector_type(8)));
typedef float f32x4 __attribute__((ext_vector_type(4)));

static __device__ __forceinline__ float sigmoidf_(float z) { return 1.f / (1.f + expf(-z)); }

static __device__ __forceinline__ ushort_t f2bf(float f) {  // RNE fp32->bf16
  unsigned int u = __float_as_uint(f);
  u += 0x7fffu + ((u >> 16) & 1u);
  return (ushort_t)(u >> 16);
}

static __device__ __forceinline__ void gl_lds16(const ushort_t* g, ushort_t* l) {
  __builtin_amdgcn_global_load_lds(
      (const __attribute__((address_space(1))) unsigned int*)g,
      (__attribute__((address_space(3))) unsigned int*)l, 16, 0, 0);
}

// ---------------- fp32 -> bf16 converter (weights) ----------------
__global__ __launch_bounds__(256) void k_f2bf(const float* __restrict__ in,
                                              ushort_t* __restrict__ out, int n) {
  int i = (blockIdx.x * 256 + threadIdx.x) * 4;
  if (i >= n) return;
  float4 v = *reinterpret_cast<const float4*>(in + i);
  ushort4 o;
  o.x = f2bf(v.x); o.y = f2bf(v.y); o.z = f2bf(v.z); o.w = f2bf(v.w);
  *reinterpret_cast<ushort4*>(out + i) = o;
}

// ---------------- xmix = x + (xprev - x) * maa_x ----------------
__global__ __launch_bounds__(256) void k_xmix(const float* __restrict__ x,
                                              const float* __restrict__ maa_x,
                                              float* __restrict__ out) {
  int idx = blockIdx.x * 256 + threadIdx.x;
  int c = idx & (Cdim - 1);
  int bt = idx >> 10;
  float xv = x[idx];
  float xp = ((bt & (Tn - 1)) == 0) ? 0.f : x[idx - Cdim];
  out[idx] = xv + (xp - xv) * maa_x[c];
}

// ---------------- down-projection: out[m,n] = act(sum_k A[m,k] W[k,n]) ----------------
template <int D, bool TANH>
__global__ __launch_bounds__(256) void k_down(const float* __restrict__ A,
                                              const float* __restrict__ W,
                                              float* __restrict__ out) {
  constexpr int R = 256 / D;
  const int n = threadIdx.x % D;
  const int mi = threadIdx.x / D;
  const int m = blockIdx.x * R + mi;
  const float* a = A + (size_t)m * Cdim;
  float acc = 0.f;
  for (int k = 0; k < Cdim; k += 4) {
    float4 av = *reinterpret_cast<const float4*>(a + k);
    acc += av.x * W[(k + 0) * D + n];
    acc += av.y * W[(k + 1) * D + n];
    acc += av.z * W[(k + 2) * D + n];
    acc += av.w * W[(k + 3) * D + n];
  }
  out[(size_t)m * D + n] = TANH ? tanhf(acc) : acc;
}

// ---------------- mix-up: 4 planes -> xrg/xwa/xk fp32 + xrg/xk/xv bf16 ----------------
__global__ __launch_bounds__(256) void k_mixup(
    const float* __restrict__ x, const float* __restrict__ mixin,
    const float* __restrict__ w2,
    const float* __restrict__ brg_w, const float* __restrict__ bwa_w,
    const float* __restrict__ bk_w, const float* __restrict__ bv_w,
    float* __restrict__ xrg, float* __restrict__ xwa, float* __restrict__ xk,
    ushort_t* __restrict__ xrg_bf, ushort_t* __restrict__ xk_bf,
    ushort_t* __restrict__ xv_bf) {
  constexpr int R = 8;
  __shared__ float smix[R][128];
  const int m0 = blockIdx.x * R;
  for (int idx = threadIdx.x; idx < R * 128; idx += 256)
    smix[idx >> 7][idx & 127] = mixin[(size_t)(m0 + (idx >> 7)) * 128 + (idx & 127)];
  __syncthreads();
  for (int cc = 0; cc < 4; ++cc) {
    const int c = cc * 256 + threadIdx.x;
    float acc0[R] = {}, acc1[R] = {}, acc2[R] = {}, acc3[R] = {};
    for (int d = 0; d < 32; ++d) {
      float w0 = w2[(0 * 32 + d) * Cdim + c];
      float w1 = w2[(1 * 32 + d) * Cdim + c];
      float w2v = w2[(2 * 32 + d) * Cdim + c];
      float w3 = w2[(3 * 32 + d) * Cdim + c];
#pragma unroll
      for (int mi = 0; mi < R; ++mi) {
        acc0[mi] += smix[mi][d] * w0;
        acc1[mi] += smix[mi][32 + d] * w1;
        acc2[mi] += smix[mi][64 + d] * w2v;
        acc3[mi] += smix[mi][96 + d] * w3;
      }
    }
    float brg = brg_w[c], bwa = bwa_w[c], bk = bk_w[c], bv = bv_w[c];
#pragma unroll
    for (int mi = 0; mi < R; ++mi) {
      int m = m0 + mi;
      size_t id = (size_t)m * Cdim + c;
      float xvv = x[id];
      float xp = ((m & (Tn - 1)) == 0) ? 0.f : x[id - Cdim];
      float xx = xp - xvv;
      float vrg = xvv + xx * (brg + acc0[mi]);
      float vwa = xvv + xx * (bwa + acc1[mi]);
      float vk = xvv + xx * (bk + acc2[mi]);
      float vv = xvv + xx * (bv + acc3[mi]);
      xrg[id] = vrg;
      xwa[id] = vwa;
      xk[id] = vk;
      xrg_bf[id] = f2bf(vrg);
      xk_bf[id] = f2bf(vk);
      xv_bf[id] = f2bf(vv);
    }
  }
}

// ---------------- bf16 MFMA GEMM: C[m,n] = sum_k A[m,k] * Bw[n,k] ----------------
// 128x128 tile, BK=64, 4 waves (2x2 of 64x64), T2 XOR-swizzled LDS,
// global_load_lds(16B) staging, 2-phase pipeline (stage t+1 || compute t).
__global__ __launch_bounds__(256) void k_gemm_mfma(
    const ushort_t* __restrict__ A, const ushort_t* __restrict__ Bw,
    float* __restrict__ C, int M, int Ncols, int K) {
  __shared__ ushort_t sh[32768];  // 2 bufs x (A 8K + B 8K ushorts) = 64 KiB
  const int tid = threadIdx.x;
  const int lane = tid & 63;
  const int wave = tid >> 6;
  const int wr = wave >> 1, wc = wave & 1;
  const int m0 = blockIdx.x * 128, n0 = blockIdx.y * 128;
  const int NT = K >> 6;
  const ushort_t* gA = A + (size_t)m0 * K;
  const ushort_t* gB = Bw + (size_t)n0 * K;
  // staging: linear LDS slot s=(wave*4+q)*512+lane*8 holds (row,kb_data) with
  // kb_data = kb_slot ^ (row&7); read side applies the same XOR -> bank-conflict-free.
  const int srow = lane >> 3;                       // row within 8-row group
  const int kbs = (lane & 7) ^ (srow & 7);          // inverse-swizzled source chunk

  f32x4 acc[4][4];
#pragma unroll
  for (int m = 0; m < 4; ++m)
#pragma unroll
    for (int n = 0; n < 4; ++n) acc[m][n] = (f32x4){0.f, 0.f, 0.f, 0.f};

  auto stage = [&](int buf, int k0) {
    ushort_t* LA = sh + buf * 16384;
    ushort_t* LB = LA + 8192;
#pragma unroll
    for (int q = 0; q < 4; ++q) {
      int row = wave * 32 + q * 8 + srow;
      gl_lds16(gA + (size_t)row * K + k0 + kbs * 8, LA + (wave * 4 + q) * 512);
    }
#pragma unroll
    for (int q = 0; q < 4; ++q) {
      int row = wave * 32 + q * 8 + srow;
      gl_lds16(gB + (size_t)row * K + k0 + kbs * 8, LB + (wave * 4 + q) * 512);
    }
  };

  auto compute = [&](int buf) {
    const ushort_t* LA = sh + buf * 16384;
    const ushort_t* LB = LA + 8192;
    const int r15 = lane & 15;
    const int kq = lane >> 4;   // 0..3
    const int rx = lane & 7;    // XOR key (= row&7 for fragment rows)
#pragma unroll
    for (int kh = 0; kh < 2; ++kh) {
      bf16x8 af[4], bfr[4];
      const int kbsw = ((kh * 4 + kq) ^ rx) << 3;
#pragma unroll
      for (int m = 0; m < 4; ++m) {
        int row = wr * 64 + m * 16 + r15;
        af[m] = *reinterpret_cast<const bf16x8*>(&LA[row * 64 + kbsw]);
      }
#pragma unroll
      for (int n = 0; n < 4; ++n) {
        int col = wc * 64 + n * 16 + r15;
        bfr[n] = *reinterpret_cast<const bf16x8*>(&LB[col * 64 + kbsw]);
      }
#pragma unroll
      for (int m = 0; m < 4; ++m)
#pragma unroll
        for (int n = 0; n < 4; ++n)
          acc[m][n] = __builtin_amdgcn_mfma_f32_16x16x32_bf16(af[m], bfr[n], acc[m][n], 0, 0, 0);
    }
  };

  stage(0, 0);
  __syncthreads();                 // drains vmcnt(0): tile 0 ready
  for (int t = 0; t < NT; ++t) {
    int cur = t & 1;
    if (t + 1 < NT) stage(cur ^ 1, (t + 1) << 6);  // issue BEFORE compute (T3 recipe)
    compute(cur);
    __syncthreads();               // one vmcnt(0)+barrier per K-tile
  }

  const int r15 = lane & 15, rq = lane >> 4;
#pragma unroll
  for (int m = 0; m < 4; ++m) {
    int row = m0 + wr * 64 + m * 16 + rq * 4;
#pragma unroll
    for (int n = 0; n < 4; ++n) {
      int col = n0 + wc * 64 + n * 16 + r15;
#pragma unroll
      for (int j = 0; j < 4; ++j)
        C[(size_t)(row + j) * Ncols + col] = acc[m][n][j];
    }
  }
}

// ---------------- up-projection, MODE 0: decay epilogue, MODE 1: plain ----------------
template <int D, int MODE>
__global__ __launch_bounds__(256) void k_up(const float* __restrict__ MID,
                                            const float* __restrict__ W2,
                                            const float* __restrict__ bias,
                                            float* __restrict__ out) {
  constexpr int R = 8;
  __shared__ float sm[R][D];
  const int m0 = blockIdx.x * R;
  for (int idx = threadIdx.x; idx < R * D; idx += 256)
    sm[idx / D][idx % D] = MID[(size_t)(m0 + idx / D) * D + (idx % D)];
  __syncthreads();
  for (int cc = 0; cc < 4; ++cc) {
    const int c = cc * 256 + threadIdx.x;
    float acc[R] = {};
    for (int d = 0; d < D; ++d) {
      float wv = W2[(size_t)d * Cdim + c];
#pragma unroll
      for (int mi = 0; mi < R; ++mi) acc[mi] += sm[mi][d] * wv;
    }
    float bv = bias ? bias[c] : 0.f;
#pragma unroll
    for (int mi = 0; mi < R; ++mi) {
      float z = acc[mi] + bv;
      float resv;
      if (MODE == 0) resv = -log1pf(expf(-z)) - 0.5f;  // -softplus(-z)-0.5
      else resv = z;
      out[(size_t)(m0 + mi) * Cdim + c] = resv;
    }
  }
}

// ---------------- combine: kk-norm, a/ma/mk2 LoRA ups, k modification ----------------
__global__ __launch_bounds__(256) void k_combine(
    float* __restrict__ kbuf, const float* __restrict__ wdec,
    const float* __restrict__ a16, const float* __restrict__ m16,
    const float* __restrict__ mk16, const float* __restrict__ kkk16,
    const float* __restrict__ aaa_w2, const float* __restrict__ ma_w2,
    const float* __restrict__ mk_w2, const float* __restrict__ kkk_w2,
    const float* __restrict__ aaaaa, const float* __restrict__ misc_a,
    const float* __restrict__ misc_k,
    float* __restrict__ kkout, float* __restrict__ aout) {
  const int bt = blockIdx.x >> 2;
  const int h = ((blockIdx.x & 3) << 2) + (threadIdx.x >> 6);
  const int lane = threadIdx.x & 63;
  const int c = h * 64 + lane;
  const size_t idx = (size_t)bt * Cdim + c;
  const float* A16 = a16 + bt * 16;
  const float* M16 = m16 + bt * 16;
  const float* K16 = mk16 + bt * 16;
  const float* KK16 = kkk16 + bt * 16;
  float accA = 0, accM = 0, accK = 0, accKK = 0;
#pragma unroll
  for (int d = 0; d < 16; ++d) {
    accA += A16[d] * aaa_w2[d * Cdim + c];
    accM += M16[d] * ma_w2[d * Cdim + c];
    accK += K16[d] * mk_w2[d * Cdim + c];
    accKK += KK16[d] * kkk_w2[d * Cdim + c];
  }
  float kval = kbuf[idx];
  float kkraw = kval + accKK;
  float ss = kkraw * kkraw;
#pragma unroll
  for (int off = 32; off; off >>= 1) ss += __shfl_xor(ss, off, 64);
  float inv = 1.f / fmaxf(sqrtf(ss), 1e-12f);
  float kkn = kkraw * inv;
  float av = sigmoidf_(aaaaa[c] + accA);
  float mav = sigmoidf_(misc_a[c] + accM);
  float mkv = sigmoidf_(misc_k[c] + accK);
  float wv = wdec[idx];
  float kn = (kval * mav + kval * av * (1.f - mav)) * expf(fminf(wv * mkv, 0.f));
  kbuf[idx] = kn;
  kkout[idx] = kkn;
  aout[idx] = av;
}

// ---------------- wkv7 scan: 1 block per (b,h); 64 rows x 4-way K split ----------------
__global__ __launch_bounds__(256) void k_scan(
    const float* __restrict__ r, const float* __restrict__ wdec,
    const float* __restrict__ k, const float* __restrict__ v,
    const float* __restrict__ kk, const float* __restrict__ a,
    float* __restrict__ y) {
  const int b = blockIdx.x >> 4;
  const int h = blockIdx.x & 15;
  const int tid = threadIdx.x;
  const int i = tid >> 2;
  const int jc = tid & 3;
  const int role = tid >> 6;
  const int l = tid & 63;
  __shared__ __align__(16) float sr[2][64], sw[2][64], sk[2][64], saa[2][64], sbb[2][64], sv[2][64];
  float st[16];
#pragma unroll
  for (int q = 0; q < 16; ++q) st[q] = 0.f;
  size_t base = (size_t)b * Tn * Cdim + h * 64;
  float ra = 0.f, rb = 0.f;
  if (role == 0) { ra = r[base + l]; rb = k[base + l]; }
  else if (role == 1) { ra = wdec[base + l]; rb = v[base + l]; }
  else if (role == 2) { ra = kk[base + l]; rb = a[base + l]; }
  int p = 0;
  for (int t = 0; t < Tn; ++t) {
    if (role == 0) { sr[p][l] = ra; sk[p][l] = rb; }
    else if (role == 1) { sw[p][l] = expf(ra); sv[p][l] = rb; }
    else if (role == 2) { saa[p][l] = -ra; sbb[p][l] = ra * rb; }
    if (t + 1 < Tn) {
      size_t nb = base + (size_t)(t + 1) * Cdim;
      if (role == 0) { ra = r[nb + l]; rb = k[nb + l]; }
      else if (role == 1) { ra = wdec[nb + l]; rb = v[nb + l]; }
      else if (role == 2) { ra = kk[nb + l]; rb = a[nb + l]; }
    }
    __syncthreads();
    const float4* aa4 = reinterpret_cast<const float4*>(saa[p]) + jc * 4;
    const float4* w4 = reinterpret_cast<const float4*>(sw[p]) + jc * 4;
    const float4* bb4 = reinterpret_cast<const float4*>(sbb[p]) + jc * 4;
    const float4* k4 = reinterpret_cast<const float4*>(sk[p]) + jc * 4;
    const float4* r4 = reinterpret_cast<const float4*>(sr[p]) + jc * 4;
    float vi = sv[p][i];
    float sa = 0.f;
#pragma unroll
    for (int q = 0; q < 4; ++q) {
      float4 x4 = aa4[q];
      sa += x4.x * st[q * 4 + 0] + x4.y * st[q * 4 + 1] + x4.z * st[q * 4 + 2] + x4.w * st[q * 4 + 3];
    }
    sa += __shfl_xor(sa, 1, 64);
    sa += __shfl_xor(sa, 2, 64);
    float yp = 0.f;
#pragma unroll
    for (int q = 0; q < 4; ++q) {
      float4 wq = w4[q]; float4 bq = bb4[q]; float4 kq = k4[q]; float4 rq = r4[q];
      float s0 = st[q * 4 + 0] * wq.x + sa * bq.x + vi * kq.x;
      float s1 = st[q * 4 + 1] * wq.y + sa * bq.y + vi * kq.y;
      float s2 = st[q * 4 + 2] * wq.z + sa * bq.z + vi * kq.z;
      float s3 = st[q * 4 + 3] * wq.w + sa * bq.w + vi * kq.w;
      st[q * 4 + 0] = s0; st[q * 4 + 1] = s1; st[q * 4 + 2] = s2; st[q * 4 + 3] = s3;
      yp += s0 * rq.x + s1 * rq.y + s2 * rq.z + s3 * rq.w;
    }
    yp += __shfl_xor(yp, 1, 64);
    yp += __shfl_xor(yp, 2, 64);
    if (jc == 0) y[base + (size_t)t * Cdim + i] = yp;
    p ^= 1;
  }
}

// ---------------- GroupNorm + bonus + gate -> bf16 (input of out-GEMM) ----------------
__global__ __launch_bounds__(256) void k_gnout(
    const float* __restrict__ y, const float* __restrict__ r,
    const float* __restrict__ k, const float* __restrict__ v,
    const float* __restrict__ g, const float* __restrict__ faaaa,
    const float* __restrict__ lnw, const float* __restrict__ lnb,
    ushort_t* __restrict__ out_bf) {
  const int bt = blockIdx.x >> 2;
  const int h = ((blockIdx.x & 3) << 2) + (threadIdx.x >> 6);
  const int lane = threadIdx.x & 63;
  const int c = h * 64 + lane;
  const size_t idx = (size_t)bt * Cdim + c;
  float yv = y[idx];
  float mu = yv;
#pragma unroll
  for (int off = 32; off; off >>= 1) mu += __shfl_xor(mu, off, 64);
  mu *= (1.f / 64.f);
  float dv = yv - mu;
  float var = dv * dv;
#pragma unroll
  for (int off = 32; off; off >>= 1) var += __shfl_xor(var, off, 64);
  var *= (1.f / 64.f);
  float ynorm = dv * rsqrtf(var + 6.4e-4f) * lnw[c] + lnb[c];
  float rv = r[idx], kv = k[idx], vv = v[idx];
  float psum = rv * kv * faaaa[c];
#pragma unroll
  for (int off = 32; off; off >>= 1) psum += __shfl_xor(psum, off, 64);
  out_bf[idx] = f2bf((ynorm + psum * vv) * g[idx]);
}

extern "C" void kernel_launch(void* const* d_in, const int* in_sizes, int n_in,
                              void* d_out, int out_size, void* d_ws, size_t ws_size,
                              hipStream_t stream) {
  (void)in_sizes; (void)n_in; (void)out_size; (void)ws_size;
  const float* x = (const float*)d_in[0];
  const float* maa_x = (const float*)d_in[1];
  const float* maa_rg = (const float*)d_in[2];
  const float* maa_wa = (const float*)d_in[3];
  const float* maa_k = (const float*)d_in[4];
  const float* maa_v = (const float*)d_in[5];
  const float* maa_w1 = (const float*)d_in[6];
  const float* maa_w2 = (const float*)d_in[7];
  const float* tdecay = (const float*)d_in[8];
  const float* dec_w1 = (const float*)d_in[9];
  const float* dec_w2 = (const float*)d_in[10];
  const float* faaaa = (const float*)d_in[11];
  const float* aaaaa = (const float*)d_in[12];
  const float* aaa_w1 = (const float*)d_in[13];
  const float* aaa_w2 = (const float*)d_in[14];
  const float* kkk_w1 = (const float*)d_in[15];
  const float* kkk_w2 = (const float*)d_in[16];
  const float* gate_w1 = (const float*)d_in[17];
  const float* gate_w2 = (const float*)d_in[18];
  const float* ma_w1 = (const float*)d_in[19];
  const float* ma_w2 = (const float*)d_in[20];
  const float* misc_a = (const float*)d_in[21];
  const float* mk_w1 = (const float*)d_in[22];
  const float* mk_w2 = (const float*)d_in[23];
  const float* misc_k = (const float*)d_in[24];
  const float* w_r = (const float*)d_in[25];
  const float* w_k = (const float*)d_in[26];
  const float* w_v = (const float*)d_in[27];
  const float* w_o = (const float*)d_in[28];
  const float* lnw = (const float*)d_in[29];
  const float* lnb = (const float*)d_in[30];
  float* out = (float*)d_out;

  float* ws = (float*)d_ws;
  const size_t F = (size_t)BT * Cdim;  // 4M elements
  float* xrg = ws + 0 * F;             // fp32 xrg; later reused as gate-up output g
  float* xwa = ws + 1 * F;             // fp32 xwa; later reused as y
  float* xk = ws + 2 * F;              // fp32 xk
  float* xv = ws + 3 * F;              // unused as fp32; slot reused as wb (decay)
  float* rb = ws + 4 * F;              // xmix temp, then r
  float* kb = ws + 5 * F;
  float* vb = ws + 6 * F;
  float* kkb = ws + 7 * F;
  float* ab = ws + 8 * F;
  float* smalls = ws + 9 * F;
  float* mixin = smalls;                   // BT*128
  float* g128 = mixin + (size_t)BT * 128;  // BT*128
  float* d64 = g128 + (size_t)BT * 128;    // BT*64
  float* a16 = d64 + (size_t)BT * 64;      // BT*16
  float* m16 = a16 + (size_t)BT * 16;
  float* mk16 = m16 + (size_t)BT * 16;
  float* kkk16 = mk16 + (size_t)BT * 16;
  float* wb = xv;                          // decay buffer (xv fp32 slot is free)

  // bf16 (ushort) region after the smalls
  ushort_t* ub = (ushort_t*)(kkk16 + (size_t)BT * 16);
  ushort_t* xrg_bf = ub + 0 * F;
  ushort_t* xk_bf = ub + 1 * F;
  ushort_t* xv_bf = ub + 2 * F;
  ushort_t* yg_bf = ub + 3 * F;
  ushort_t* wr_bf = ub + 4 * F;
  ushort_t* wk_bf = wr_bf + (size_t)Cdim * Cdim;
  ushort_t* wv_bf = wk_bf + (size_t)Cdim * Cdim;
  ushort_t* wo_bf = wv_bf + (size_t)Cdim * Cdim;

  dim3 blk(256);
  dim3 ggrid(BT / 128, Cdim / 128);  // x = m-tile (consecutive x share the B-panel)
  const int WN = Cdim * Cdim;

  // 0. weight conversions (independent)
  k_f2bf<<<WN / 1024, blk, 0, stream>>>(w_r, wr_bf, WN);
  k_f2bf<<<WN / 1024, blk, 0, stream>>>(w_k, wk_bf, WN);
  k_f2bf<<<WN / 1024, blk, 0, stream>>>(w_v, wv_bf, WN);
  k_f2bf<<<WN / 1024, blk, 0, stream>>>(w_o, wo_bf, WN);
  // 1. xmix -> rb (temp)
  k_xmix<<<(BT * Cdim) / 256, blk, 0, stream>>>(x, maa_x, rb);
  // 2. mixin = tanh(xmix @ maa_w1)
  k_down<128, true><<<BT / 2, blk, 0, stream>>>(rb, maa_w1, mixin);
  // 3. mix-up -> xrg/xwa/xk fp32 + xrg/xk/xv bf16
  k_mixup<<<BT / 8, blk, 0, stream>>>(x, mixin, maa_w2, maa_rg, maa_wa, maa_k, maa_v,
                                      xrg, xwa, xk, xrg_bf, xk_bf, xv_bf);
  // 4. gate down (fp32 xrg)
  k_down<128, true><<<BT / 2, blk, 0, stream>>>(xrg, gate_w1, g128);
  // 5-7. big GEMMs (bf16 MFMA)
  k_gemm_mfma<<<ggrid, blk, 0, stream>>>(xrg_bf, wr_bf, rb, BT, Cdim, Cdim);
  k_gemm_mfma<<<ggrid, blk, 0, stream>>>(xk_bf, wk_bf, kb, BT, Cdim, Cdim);
  k_gemm_mfma<<<ggrid, blk, 0, stream>>>(xv_bf, wv_bf, vb, BT, Cdim, Cdim);
  // 8-12. LoRA downs (fp32)
  k_down<64, true><<<BT / 4, blk, 0, stream>>>(xwa, dec_w1, d64);
  k_down<16, false><<<BT / 16, blk, 0, stream>>>(xwa, aaa_w1, a16);
  k_down<16, false><<<BT / 16, blk, 0, stream>>>(xwa, ma_w1, m16);
  k_down<16, true><<<BT / 16, blk, 0, stream>>>(xk, kkk_w1, kkk16);
  k_down<16, false><<<BT / 16, blk, 0, stream>>>(xk, mk_w1, mk16);
  // 13. decay up -> wb
  k_up<64, 0><<<BT / 8, blk, 0, stream>>>(d64, dec_w2, tdecay, wb);
  // 14. gate up -> xrg slot (fp32 xrg dead after gate down)
  k_up<128, 1><<<BT / 8, blk, 0, stream>>>(g128, gate_w2, nullptr, xrg);
  // 15. combine
  k_combine<<<BT * 4, blk, 0, stream>>>(kb, wb, a16, m16, mk16, kkk16,
                                        aaa_w2, ma_w2, mk_w2, kkk_w2,
                                        aaaaa, misc_a, misc_k, kkb, ab);
  // 16. wkv7 scan -> y (xwa slot)
  k_scan<<<64, blk, 0, stream>>>(rb, wb, kb, vb, kkb, ab, xwa);
  // 17. GN + bonus + gate -> yg_bf (bf16)
  k_gnout<<<BT * 4, blk, 0, stream>>>(xwa, rb, kb, vb, xrg, faaaa, lnw, lnb, yg_bf);
  // 18. output GEMM -> d_out (fp32)
  k_gemm_mfma<<<ggrid, blk, 0, stream>>>(yg_bf, wo_bf, out, BT, Cdim, Cdim);
}

// Round 4
// 1367.731 us; speedup vs baseline: 1.2990x; 1.2990x over previous
//
#include <hip/hip_runtime.h>
#include <math.h>

#define BT   4096
#define Cdim 1024
#define Hn   16
#define Nelem 64
#define Tn   1024

typedef unsigned short ushort_t;
typedef short bf16x8 __attribute__((ext_vector_type(8)));
typedef float f32x4 __attribute__((ext_vector_type(4)));

static __device__ __forceinline__ float sigmoidf_(float z) { return 1.f / (1.f + expf(-z)); }

static __device__ __forceinline__ ushort_t f2bf(float f) {  // RNE fp32->bf16
  unsigned int u = __float_as_uint(f);
  u += 0x7fffu + ((u >> 16) & 1u);
  return (ushort_t)(u >> 16);
}

static __device__ __forceinline__ void gl_lds16(const ushort_t* g, ushort_t* l) {
  __builtin_amdgcn_global_load_lds(
      (const __attribute__((address_space(1))) unsigned int*)g,
      (__attribute__((address_space(3))) unsigned int*)l, 16, 0, 0);
}

// ---------------- fp32 -> bf16 converter (weights) ----------------
__global__ __launch_bounds__(256) void k_f2bf(const float* __restrict__ in,
                                              ushort_t* __restrict__ out, int n) {
  int i = (blockIdx.x * 256 + threadIdx.x) * 4;
  if (i >= n) return;
  float4 v = *reinterpret_cast<const float4*>(in + i);
  ushort4 o;
  o.x = f2bf(v.x); o.y = f2bf(v.y); o.z = f2bf(v.z); o.w = f2bf(v.w);
  *reinterpret_cast<ushort4*>(out + i) = o;
}

// ---------------- xmix = x + (xprev - x) * maa_x ----------------
__global__ __launch_bounds__(256) void k_xmix(const float* __restrict__ x,
                                              const float* __restrict__ maa_x,
                                              float* __restrict__ out) {
  int idx = blockIdx.x * 256 + threadIdx.x;
  int c = idx & (Cdim - 1);
  int bt = idx >> 10;
  float xv = x[idx];
  float xp = ((bt & (Tn - 1)) == 0) ? 0.f : x[idx - Cdim];
  out[idx] = xv + (xp - xv) * maa_x[c];
}

// ---------------- down-projection: out[m,n] = act(sum_k A[m,k] W[k,n]) ----------------
template <int D, bool TANH>
__global__ __launch_bounds__(256) void k_down(const float* __restrict__ A,
                                              const float* __restrict__ W,
                                              float* __restrict__ out) {
  constexpr int R = 256 / D;
  const int n = threadIdx.x % D;
  const int mi = threadIdx.x / D;
  const int m = blockIdx.x * R + mi;
  const float* a = A + (size_t)m * Cdim;
  float acc = 0.f;
  for (int k = 0; k < Cdim; k += 4) {
    float4 av = *reinterpret_cast<const float4*>(a + k);
    acc += av.x * W[(k + 0) * D + n];
    acc += av.y * W[(k + 1) * D + n];
    acc += av.z * W[(k + 2) * D + n];
    acc += av.w * W[(k + 3) * D + n];
  }
  out[(size_t)m * D + n] = TANH ? tanhf(acc) : acc;
}

// ---------------- mix-up: 4 planes -> xrg/xwa/xk fp32 + xrg/xk/xv bf16 ----------------
__global__ __launch_bounds__(256) void k_mixup(
    const float* __restrict__ x, const float* __restrict__ mixin,
    const float* __restrict__ w2,
    const float* __restrict__ brg_w, const float* __restrict__ bwa_w,
    const float* __restrict__ bk_w, const float* __restrict__ bv_w,
    float* __restrict__ xrg, float* __restrict__ xwa, float* __restrict__ xk,
    ushort_t* __restrict__ xrg_bf, ushort_t* __restrict__ xk_bf,
    ushort_t* __restrict__ xv_bf) {
  constexpr int R = 8;
  __shared__ float smix[R][128];
  const int m0 = blockIdx.x * R;
  for (int idx = threadIdx.x; idx < R * 128; idx += 256)
    smix[idx >> 7][idx & 127] = mixin[(size_t)(m0 + (idx >> 7)) * 128 + (idx & 127)];
  __syncthreads();
  for (int cc = 0; cc < 4; ++cc) {
    const int c = cc * 256 + threadIdx.x;
    float acc0[R] = {}, acc1[R] = {}, acc2[R] = {}, acc3[R] = {};
    for (int d = 0; d < 32; ++d) {
      float w0 = w2[(0 * 32 + d) * Cdim + c];
      float w1 = w2[(1 * 32 + d) * Cdim + c];
      float w2v = w2[(2 * 32 + d) * Cdim + c];
      float w3 = w2[(3 * 32 + d) * Cdim + c];
#pragma unroll
      for (int mi = 0; mi < R; ++mi) {
        acc0[mi] += smix[mi][d] * w0;
        acc1[mi] += smix[mi][32 + d] * w1;
        acc2[mi] += smix[mi][64 + d] * w2v;
        acc3[mi] += smix[mi][96 + d] * w3;
      }
    }
    float brg = brg_w[c], bwa = bwa_w[c], bk = bk_w[c], bv = bv_w[c];
#pragma unroll
    for (int mi = 0; mi < R; ++mi) {
      int m = m0 + mi;
      size_t id = (size_t)m * Cdim + c;
      float xvv = x[id];
      float xp = ((m & (Tn - 1)) == 0) ? 0.f : x[id - Cdim];
      float xx = xp - xvv;
      float vrg = xvv + xx * (brg + acc0[mi]);
      float vwa = xvv + xx * (bwa + acc1[mi]);
      float vk = xvv + xx * (bk + acc2[mi]);
      float vv = xvv + xx * (bv + acc3[mi]);
      xrg[id] = vrg;
      xwa[id] = vwa;
      xk[id] = vk;
      xrg_bf[id] = f2bf(vrg);
      xk_bf[id] = f2bf(vk);
      xv_bf[id] = f2bf(vv);
    }
  }
}

// ---------------- bf16 MFMA GEMM: C[m,n] = sum_k A[m,k] * Bw[n,k] ----------------
__global__ __launch_bounds__(256) void k_gemm_mfma(
    const ushort_t* __restrict__ A, const ushort_t* __restrict__ Bw,
    float* __restrict__ C, int M, int Ncols, int K) {
  __shared__ ushort_t sh[32768];  // 2 bufs x (A 8K + B 8K ushorts) = 64 KiB
  const int tid = threadIdx.x;
  const int lane = tid & 63;
  const int wave = tid >> 6;
  const int wr = wave >> 1, wc = wave & 1;
  const int m0 = blockIdx.x * 128, n0 = blockIdx.y * 128;
  const int NT = K >> 6;
  const ushort_t* gA = A + (size_t)m0 * K;
  const ushort_t* gB = Bw + (size_t)n0 * K;
  const int srow = lane >> 3;
  const int kbs = (lane & 7) ^ (srow & 7);

  f32x4 acc[4][4];
#pragma unroll
  for (int m = 0; m < 4; ++m)
#pragma unroll
    for (int n = 0; n < 4; ++n) acc[m][n] = (f32x4){0.f, 0.f, 0.f, 0.f};

  auto stage = [&](int buf, int k0) {
    ushort_t* LA = sh + buf * 16384;
    ushort_t* LB = LA + 8192;
#pragma unroll
    for (int q = 0; q < 4; ++q) {
      int row = wave * 32 + q * 8 + srow;
      gl_lds16(gA + (size_t)row * K + k0 + kbs * 8, LA + (wave * 4 + q) * 512);
    }
#pragma unroll
    for (int q = 0; q < 4; ++q) {
      int row = wave * 32 + q * 8 + srow;
      gl_lds16(gB + (size_t)row * K + k0 + kbs * 8, LB + (wave * 4 + q) * 512);
    }
  };

  auto compute = [&](int buf) {
    const ushort_t* LA = sh + buf * 16384;
    const ushort_t* LB = LA + 8192;
    const int r15 = lane & 15;
    const int kq = lane >> 4;
    const int rx = lane & 7;
#pragma unroll
    for (int kh = 0; kh < 2; ++kh) {
      bf16x8 af[4], bfr[4];
      const int kbsw = ((kh * 4 + kq) ^ rx) << 3;
#pragma unroll
      for (int m = 0; m < 4; ++m) {
        int row = wr * 64 + m * 16 + r15;
        af[m] = *reinterpret_cast<const bf16x8*>(&LA[row * 64 + kbsw]);
      }
#pragma unroll
      for (int n = 0; n < 4; ++n) {
        int col = wc * 64 + n * 16 + r15;
        bfr[n] = *reinterpret_cast<const bf16x8*>(&LB[col * 64 + kbsw]);
      }
#pragma unroll
      for (int m = 0; m < 4; ++m)
#pragma unroll
        for (int n = 0; n < 4; ++n)
          acc[m][n] = __builtin_amdgcn_mfma_f32_16x16x32_bf16(af[m], bfr[n], acc[m][n], 0, 0, 0);
    }
  };

  stage(0, 0);
  __syncthreads();
  for (int t = 0; t < NT; ++t) {
    int cur = t & 1;
    if (t + 1 < NT) stage(cur ^ 1, (t + 1) << 6);
    compute(cur);
    __syncthreads();
  }

  const int r15 = lane & 15, rq = lane >> 4;
#pragma unroll
  for (int m = 0; m < 4; ++m) {
    int row = m0 + wr * 64 + m * 16 + rq * 4;
#pragma unroll
    for (int n = 0; n < 4; ++n) {
      int col = n0 + wc * 64 + n * 16 + r15;
#pragma unroll
      for (int j = 0; j < 4; ++j)
        C[(size_t)(row + j) * Ncols + col] = acc[m][n][j];
    }
  }
}

// ---------------- up-projection, MODE 0: decay epilogue, MODE 1: plain ----------------
template <int D, int MODE>
__global__ __launch_bounds__(256) void k_up(const float* __restrict__ MID,
                                            const float* __restrict__ W2,
                                            const float* __restrict__ bias,
                                            float* __restrict__ out) {
  constexpr int R = 8;
  __shared__ float sm[R][D];
  const int m0 = blockIdx.x * R;
  for (int idx = threadIdx.x; idx < R * D; idx += 256)
    sm[idx / D][idx % D] = MID[(size_t)(m0 + idx / D) * D + (idx % D)];
  __syncthreads();
  for (int cc = 0; cc < 4; ++cc) {
    const int c = cc * 256 + threadIdx.x;
    float acc[R] = {};
    for (int d = 0; d < D; ++d) {
      float wv = W2[(size_t)d * Cdim + c];
#pragma unroll
      for (int mi = 0; mi < R; ++mi) acc[mi] += sm[mi][d] * wv;
    }
    float bv = bias ? bias[c] : 0.f;
#pragma unroll
    for (int mi = 0; mi < R; ++mi) {
      float z = acc[mi] + bv;
      float resv;
      if (MODE == 0) resv = -log1pf(expf(-z)) - 0.5f;  // -softplus(-z)-0.5
      else resv = z;
      out[(size_t)(m0 + mi) * Cdim + c] = resv;
    }
  }
}

// ---------------- combine: kk-norm, a/ma/mk2 LoRA ups, k-mod, scan precompute ----------
// Also: wdec <- exp(wdec) IN PLACE (scan wants decay factors, wdec dead after this),
//       bout <- kk_norm * a (the b_t vector of the scan).
__global__ __launch_bounds__(256) void k_combine(
    float* __restrict__ kbuf, float* __restrict__ wdec,
    const float* __restrict__ a16, const float* __restrict__ m16,
    const float* __restrict__ mk16, const float* __restrict__ kkk16,
    const float* __restrict__ aaa_w2, const float* __restrict__ ma_w2,
    const float* __restrict__ mk_w2, const float* __restrict__ kkk_w2,
    const float* __restrict__ aaaaa, const float* __restrict__ misc_a,
    const float* __restrict__ misc_k,
    float* __restrict__ kkout, float* __restrict__ bout) {
  const int bt = blockIdx.x >> 2;
  const int h = ((blockIdx.x & 3) << 2) + (threadIdx.x >> 6);
  const int lane = threadIdx.x & 63;
  const int c = h * 64 + lane;
  const size_t idx = (size_t)bt * Cdim + c;
  const float* A16 = a16 + bt * 16;
  const float* M16 = m16 + bt * 16;
  const float* K16 = mk16 + bt * 16;
  const float* KK16 = kkk16 + bt * 16;
  float accA = 0, accM = 0, accK = 0, accKK = 0;
#pragma unroll
  for (int d = 0; d < 16; ++d) {
    accA += A16[d] * aaa_w2[d * Cdim + c];
    accM += M16[d] * ma_w2[d * Cdim + c];
    accK += K16[d] * mk_w2[d * Cdim + c];
    accKK += KK16[d] * kkk_w2[d * Cdim + c];
  }
  float kval = kbuf[idx];
  float kkraw = kval + accKK;
  float ss = kkraw * kkraw;
#pragma unroll
  for (int off = 32; off; off >>= 1) ss += __shfl_xor(ss, off, 64);
  float inv = 1.f / fmaxf(sqrtf(ss), 1e-12f);
  float kkn = kkraw * inv;
  float av = sigmoidf_(aaaaa[c] + accA);
  float mav = sigmoidf_(misc_a[c] + accM);
  float mkv = sigmoidf_(misc_k[c] + accK);
  float wv = wdec[idx];
  float kn = (kval * mav + kval * av * (1.f - mav)) * expf(fminf(wv * mkv, 0.f));
  kbuf[idx] = kn;
  kkout[idx] = kkn;
  bout[idx] = kkn * av;
  wdec[idx] = expf(wv);
}

// ---------------- wkv7 scan v2: barrier-free steps, chunked LDS staging -------------
// 128 blocks = (b,h,half): 32 state rows per block, 8 lanes per row.
// Chunk = 16 timesteps of {r, d=exp(w), k, kk, b, v} staged into LDS (double buffer);
// one __syncthreads per chunk; loads for chunk c+1 issued before computing chunk c.
__global__ __launch_bounds__(256) void k_scan(
    const float* __restrict__ r, const float* __restrict__ wexp,
    const float* __restrict__ k, const float* __restrict__ kk,
    const float* __restrict__ bb, const float* __restrict__ v,
    float* __restrict__ y) {
  __shared__ float lds[2][6][16][64];  // 48 KiB
  const int bh = blockIdx.x >> 1;
  const int half = blockIdx.x & 1;
  const int b = bh >> 4, h = bh & 15;
  const int tid = threadIdx.x;
  const int jc = tid & 7;          // 8 lanes per state row
  const int j0 = jc * 8;           // this lane's 8-wide j slice
  const int i = half * 32 + (tid >> 3);  // state row (0..63)

  // staging coords: thread tid loads (step = tid>>4, j = (tid&15)*4) of each array
  const int s_step = tid >> 4;
  const int s_j = (tid & 15) * 4;
  const size_t srcbase = (size_t)b * Tn * Cdim + h * 64 + s_j;
  const size_t ybase = (size_t)b * Tn * Cdim + h * 64;

  float s0 = 0.f, s1 = 0.f, s2 = 0.f, s3 = 0.f, s4 = 0.f, s5 = 0.f, s6 = 0.f, s7 = 0.f;
  float4 g0, g1, g2, g3, g4, g5;

#define LOADC(c_) {                                                   \
    size_t o = srcbase + (size_t)((c_) * 16 + s_step) * Cdim;         \
    g0 = *reinterpret_cast<const float4*>(r + o);                     \
    g1 = *reinterpret_cast<const float4*>(wexp + o);                  \
    g2 = *reinterpret_cast<const float4*>(k + o);                     \
    g3 = *reinterpret_cast<const float4*>(kk + o);                    \
    g4 = *reinterpret_cast<const float4*>(bb + o);                    \
    g5 = *reinterpret_cast<const float4*>(v + o);                     \
  }
#define WRITEC(bi_) {                                                 \
    *reinterpret_cast<float4*>(&lds[bi_][0][s_step][s_j]) = g0;       \
    *reinterpret_cast<float4*>(&lds[bi_][1][s_step][s_j]) = g1;       \
    *reinterpret_cast<float4*>(&lds[bi_][2][s_step][s_j]) = g2;       \
    *reinterpret_cast<float4*>(&lds[bi_][3][s_step][s_j]) = g3;       \
    *reinterpret_cast<float4*>(&lds[bi_][4][s_step][s_j]) = g4;       \
    *reinterpret_cast<float4*>(&lds[bi_][5][s_step][s_j]) = g5;       \
  }

  LOADC(0);
  WRITEC(0);
  __syncthreads();

  for (int c = 0; c < Tn / 16; ++c) {
    const int cur = c & 1;
    if (c + 1 < Tn / 16) LOADC(c + 1);
    const float(*Lc)[16][64] = lds[cur];
    const int c16 = c * 16;
#pragma unroll
    for (int s = 0; s < 16; ++s) {
      const float4 Rv0 = *reinterpret_cast<const float4*>(&Lc[0][s][j0]);
      const float4 Rv1 = *reinterpret_cast<const float4*>(&Lc[0][s][j0 + 4]);
      const float4 Wv0 = *reinterpret_cast<const float4*>(&Lc[1][s][j0]);
      const float4 Wv1 = *reinterpret_cast<const float4*>(&Lc[1][s][j0 + 4]);
      const float4 Kv0 = *reinterpret_cast<const float4*>(&Lc[2][s][j0]);
      const float4 Kv1 = *reinterpret_cast<const float4*>(&Lc[2][s][j0 + 4]);
      const float4 Av0 = *reinterpret_cast<const float4*>(&Lc[3][s][j0]);
      const float4 Av1 = *reinterpret_cast<const float4*>(&Lc[3][s][j0 + 4]);
      const float4 Bv0 = *reinterpret_cast<const float4*>(&Lc[4][s][j0]);
      const float4 Bv1 = *reinterpret_cast<const float4*>(&Lc[4][s][j0 + 4]);
      const float vi = Lc[5][s][i];
      // ssum = sum_j S[i,j]*kk[j]  (a_t = -kk; sign folded below)
      float p0 = s0 * Av0.x + s1 * Av0.y + s2 * Av0.z + s3 * Av0.w;
      float p1 = s4 * Av1.x + s5 * Av1.y + s6 * Av1.z + s7 * Av1.w;
      float ssum = p0 + p1;
      ssum += __shfl_xor(ssum, 1, 64);
      ssum += __shfl_xor(ssum, 2, 64);
      ssum += __shfl_xor(ssum, 4, 64);
      // S = S*d - ssum*b + v*k ; y = sum_j S*r
      s0 = s0 * Wv0.x + (vi * Kv0.x - ssum * Bv0.x);
      s1 = s1 * Wv0.y + (vi * Kv0.y - ssum * Bv0.y);
      s2 = s2 * Wv0.z + (vi * Kv0.z - ssum * Bv0.z);
      s3 = s3 * Wv0.w + (vi * Kv0.w - ssum * Bv0.w);
      s4 = s4 * Wv1.x + (vi * Kv1.x - ssum * Bv1.x);
      s5 = s5 * Wv1.y + (vi * Kv1.y - ssum * Bv1.y);
      s6 = s6 * Wv1.z + (vi * Kv1.z - ssum * Bv1.z);
      s7 = s7 * Wv1.w + (vi * Kv1.w - ssum * Bv1.w);
      float q0 = s0 * Rv0.x + s1 * Rv0.y + s2 * Rv0.z + s3 * Rv0.w;
      float q1 = s4 * Rv1.x + s5 * Rv1.y + s6 * Rv1.z + s7 * Rv1.w;
      float yp = q0 + q1;
      yp += __shfl_xor(yp, 1, 64);
      yp += __shfl_xor(yp, 2, 64);
      yp += __shfl_xor(yp, 4, 64);
      if (jc == 0) y[ybase + (size_t)(c16 + s) * Cdim + i] = yp;
    }
    if (c + 1 < Tn / 16) WRITEC((c + 1) & 1);
    __syncthreads();
  }
#undef LOADC
#undef WRITEC
}

// ---------------- GroupNorm + bonus + gate -> bf16 (input of out-GEMM) ----------------
__global__ __launch_bounds__(256) void k_gnout(
    const float* __restrict__ y, const float* __restrict__ r,
    const float* __restrict__ k, const float* __restrict__ v,
    const float* __restrict__ g, const float* __restrict__ faaaa,
    const float* __restrict__ lnw, const float* __restrict__ lnb,
    ushort_t* __restrict__ out_bf) {
  const int bt = blockIdx.x >> 2;
  const int h = ((blockIdx.x & 3) << 2) + (threadIdx.x >> 6);
  const int lane = threadIdx.x & 63;
  const int c = h * 64 + lane;
  const size_t idx = (size_t)bt * Cdim + c;
  float yv = y[idx];
  float mu = yv;
#pragma unroll
  for (int off = 32; off; off >>= 1) mu += __shfl_xor(mu, off, 64);
  mu *= (1.f / 64.f);
  float dv = yv - mu;
  float var = dv * dv;
#pragma unroll
  for (int off = 32; off; off >>= 1) var += __shfl_xor(var, off, 64);
  var *= (1.f / 64.f);
  float ynorm = dv * rsqrtf(var + 6.4e-4f) * lnw[c] + lnb[c];
  float rv = r[idx], kv = k[idx], vv = v[idx];
  float psum = rv * kv * faaaa[c];
#pragma unroll
  for (int off = 32; off; off >>= 1) psum += __shfl_xor(psum, off, 64);
  out_bf[idx] = f2bf((ynorm + psum * vv) * g[idx]);
}

extern "C" void kernel_launch(void* const* d_in, const int* in_sizes, int n_in,
                              void* d_out, int out_size, void* d_ws, size_t ws_size,
                              hipStream_t stream) {
  (void)in_sizes; (void)n_in; (void)out_size; (void)ws_size;
  const float* x = (const float*)d_in[0];
  const float* maa_x = (const float*)d_in[1];
  const float* maa_rg = (const float*)d_in[2];
  const float* maa_wa = (const float*)d_in[3];
  const float* maa_k = (const float*)d_in[4];
  const float* maa_v = (const float*)d_in[5];
  const float* maa_w1 = (const float*)d_in[6];
  const float* maa_w2 = (const float*)d_in[7];
  const float* tdecay = (const float*)d_in[8];
  const float* dec_w1 = (const float*)d_in[9];
  const float* dec_w2 = (const float*)d_in[10];
  const float* faaaa = (const float*)d_in[11];
  const float* aaaaa = (const float*)d_in[12];
  const float* aaa_w1 = (const float*)d_in[13];
  const float* aaa_w2 = (const float*)d_in[14];
  const float* kkk_w1 = (const float*)d_in[15];
  const float* kkk_w2 = (const float*)d_in[16];
  const float* gate_w1 = (const float*)d_in[17];
  const float* gate_w2 = (const float*)d_in[18];
  const float* ma_w1 = (const float*)d_in[19];
  const float* ma_w2 = (const float*)d_in[20];
  const float* misc_a = (const float*)d_in[21];
  const float* mk_w1 = (const float*)d_in[22];
  const float* mk_w2 = (const float*)d_in[23];
  const float* misc_k = (const float*)d_in[24];
  const float* w_r = (const float*)d_in[25];
  const float* w_k = (const float*)d_in[26];
  const float* w_v = (const float*)d_in[27];
  const float* w_o = (const float*)d_in[28];
  const float* lnw = (const float*)d_in[29];
  const float* lnb = (const float*)d_in[30];
  float* out = (float*)d_out;

  float* ws = (float*)d_ws;
  const size_t F = (size_t)BT * Cdim;  // 4M elements
  float* xrg = ws + 0 * F;             // fp32 xrg; later reused as gate-up output g
  float* xwa = ws + 1 * F;             // fp32 xwa; later reused as y
  float* xk = ws + 2 * F;              // fp32 xk
  float* xv = ws + 3 * F;              // slot reused as wb (decay, then exp(decay))
  float* rb = ws + 4 * F;              // xmix temp, then r
  float* kb = ws + 5 * F;
  float* vb = ws + 6 * F;
  float* kkb = ws + 7 * F;
  float* ab = ws + 8 * F;              // b = kk*a for the scan
  float* smalls = ws + 9 * F;
  float* mixin = smalls;                   // BT*128
  float* g128 = mixin + (size_t)BT * 128;  // BT*128
  float* d64 = g128 + (size_t)BT * 128;    // BT*64
  float* a16 = d64 + (size_t)BT * 64;      // BT*16
  float* m16 = a16 + (size_t)BT * 16;
  float* mk16 = m16 + (size_t)BT * 16;
  float* kkk16 = mk16 + (size_t)BT * 16;
  float* wb = xv;

  // bf16 (ushort) region after the smalls
  ushort_t* ub = (ushort_t*)(kkk16 + (size_t)BT * 16);
  ushort_t* xrg_bf = ub + 0 * F;
  ushort_t* xk_bf = ub + 1 * F;
  ushort_t* xv_bf = ub + 2 * F;
  ushort_t* yg_bf = ub + 3 * F;
  ushort_t* wr_bf = ub + 4 * F;
  ushort_t* wk_bf = wr_bf + (size_t)Cdim * Cdim;
  ushort_t* wv_bf = wk_bf + (size_t)Cdim * Cdim;
  ushort_t* wo_bf = wv_bf + (size_t)Cdim * Cdim;

  dim3 blk(256);
  dim3 ggrid(BT / 128, Cdim / 128);
  const int WN = Cdim * Cdim;

  // 0. weight conversions
  k_f2bf<<<WN / 1024, blk, 0, stream>>>(w_r, wr_bf, WN);
  k_f2bf<<<WN / 1024, blk, 0, stream>>>(w_k, wk_bf, WN);
  k_f2bf<<<WN / 1024, blk, 0, stream>>>(w_v, wv_bf, WN);
  k_f2bf<<<WN / 1024, blk, 0, stream>>>(w_o, wo_bf, WN);
  // 1. xmix -> rb (temp)
  k_xmix<<<(BT * Cdim) / 256, blk, 0, stream>>>(x, maa_x, rb);
  // 2. mixin = tanh(xmix @ maa_w1)
  k_down<128, true><<<BT / 2, blk, 0, stream>>>(rb, maa_w1, mixin);
  // 3. mix-up
  k_mixup<<<BT / 8, blk, 0, stream>>>(x, mixin, maa_w2, maa_rg, maa_wa, maa_k, maa_v,
                                      xrg, xwa, xk, xrg_bf, xk_bf, xv_bf);
  // 4. gate down
  k_down<128, true><<<BT / 2, blk, 0, stream>>>(xrg, gate_w1, g128);
  // 5-7. big GEMMs (bf16 MFMA)
  k_gemm_mfma<<<ggrid, blk, 0, stream>>>(xrg_bf, wr_bf, rb, BT, Cdim, Cdim);
  k_gemm_mfma<<<ggrid, blk, 0, stream>>>(xk_bf, wk_bf, kb, BT, Cdim, Cdim);
  k_gemm_mfma<<<ggrid, blk, 0, stream>>>(xv_bf, wv_bf, vb, BT, Cdim, Cdim);
  // 8-12. LoRA downs
  k_down<64, true><<<BT / 4, blk, 0, stream>>>(xwa, dec_w1, d64);
  k_down<16, false><<<BT / 16, blk, 0, stream>>>(xwa, aaa_w1, a16);
  k_down<16, false><<<BT / 16, blk, 0, stream>>>(xwa, ma_w1, m16);
  k_down<16, true><<<BT / 16, blk, 0, stream>>>(xk, kkk_w1, kkk16);
  k_down<16, false><<<BT / 16, blk, 0, stream>>>(xk, mk_w1, mk16);
  // 13. decay up -> wb
  k_up<64, 0><<<BT / 8, blk, 0, stream>>>(d64, dec_w2, tdecay, wb);
  // 14. gate up -> xrg slot
  k_up<128, 1><<<BT / 8, blk, 0, stream>>>(g128, gate_w2, nullptr, xrg);
  // 15. combine (k-mod in place; wb <- exp(wb); ab <- kk*a)
  k_combine<<<BT * 4, blk, 0, stream>>>(kb, wb, a16, m16, mk16, kkk16,
                                        aaa_w2, ma_w2, mk_w2, kkk_w2,
                                        aaaaa, misc_a, misc_k, kkb, ab);
  // 16. wkv7 scan v2 -> y (xwa slot)
  k_scan<<<128, blk, 0, stream>>>(rb, wb, kb, kkb, ab, vb, xwa);
  // 17. GN + bonus + gate -> yg_bf
  k_gnout<<<BT * 4, blk, 0, stream>>>(xwa, rb, kb, vb, xrg, faaaa, lnw, lnb, yg_bf);
  // 18. output GEMM -> d_out
  k_gemm_mfma<<<ggrid, blk, 0, stream>>>(yg_bf, wo_bf, out, BT, Cdim, Cdim);
}

// Round 5
// 1268.682 us; speedup vs baseline: 1.4004x; 1.0781x over previous
//
#include <hip/hip_runtime.h>
#include <math.h>

#define BT   4096
#define Cdim 1024
#define Hn   16
#define Nelem 64
#define Tn   1024

typedef unsigned short ushort_t;
typedef short bf16x8 __attribute__((ext_vector_type(8)));
typedef float f32x4 __attribute__((ext_vector_type(4)));

static __device__ __forceinline__ float sigmoidf_(float z) { return 1.f / (1.f + expf(-z)); }

static __device__ __forceinline__ ushort_t f2bf(float f) {  // RNE fp32->bf16
  unsigned int u = __float_as_uint(f);
  u += 0x7fffu + ((u >> 16) & 1u);
  return (ushort_t)(u >> 16);
}

static __device__ __forceinline__ void gl_lds16(const ushort_t* g, ushort_t* l) {
  __builtin_amdgcn_global_load_lds(
      (const __attribute__((address_space(1))) unsigned int*)g,
      (__attribute__((address_space(3))) unsigned int*)l, 16, 0, 0);
}

// DPP cross-lane add: x + lane-permuted x. CTRL: 0xB1=xor1, 0x4E=xor2, 0x141=half-mirror(xor7)
template <int CTRL>
static __device__ __forceinline__ float dppadd(float x) {
  int t = __builtin_amdgcn_mov_dpp(__float_as_int(x), CTRL, 0xF, 0xF, true);
  return x + __int_as_float(t);
}

// ---------------- fp32 -> bf16: all 4 weight matrices in one launch ----------------
__global__ __launch_bounds__(256) void k_f2bf4(
    const float* __restrict__ w0, const float* __restrict__ w1,
    const float* __restrict__ w2, const float* __restrict__ w3,
    ushort_t* __restrict__ o0, ushort_t* __restrict__ o1,
    ushort_t* __restrict__ o2, ushort_t* __restrict__ o3) {
  int idx4 = blockIdx.x * 256 + threadIdx.x;  // each handles 4 elements
  int which = idx4 >> 18;                     // 1M elements = 256K float4 per matrix
  int loc = (idx4 & 0x3FFFF) * 4;
  const float* in = which == 0 ? w0 : which == 1 ? w1 : which == 2 ? w2 : w3;
  ushort_t* out = which == 0 ? o0 : which == 1 ? o1 : which == 2 ? o2 : o3;
  float4 v = *reinterpret_cast<const float4*>(in + loc);
  ushort4 o;
  o.x = f2bf(v.x); o.y = f2bf(v.y); o.z = f2bf(v.z); o.w = f2bf(v.w);
  *reinterpret_cast<ushort4*>(out + loc) = o;
}

// ---------------- fused xmix + mixin = tanh(xmix @ maa_w1) ----------------
__global__ __launch_bounds__(256) void k_mixdown(const float* __restrict__ x,
                                                 const float* __restrict__ maa_x,
                                                 const float* __restrict__ W,
                                                 float* __restrict__ out) {
  __shared__ float rowlds[2][1024];
  const int m0 = blockIdx.x * 2;
  for (int idx = threadIdx.x; idx < 2048; idx += 256) {
    int mi = idx >> 10, c = idx & 1023;
    int m = m0 + mi;
    size_t id = (size_t)m * Cdim + c;
    float xv = x[id];
    float xp = ((m & (Tn - 1)) == 0) ? 0.f : x[id - Cdim];
    rowlds[mi][c] = xv + (xp - xv) * maa_x[c];
  }
  __syncthreads();
  const int n = threadIdx.x & 127, mi = threadIdx.x >> 7;
  float acc = 0.f;
  for (int k = 0; k < Cdim; k += 4) {
    float4 av = *reinterpret_cast<const float4*>(&rowlds[mi][k]);
    acc += av.x * W[(k + 0) * 128 + n];
    acc += av.y * W[(k + 1) * 128 + n];
    acc += av.z * W[(k + 2) * 128 + n];
    acc += av.w * W[(k + 3) * 128 + n];
  }
  out[(size_t)(m0 + mi) * 128 + n] = tanhf(acc);
}

// ---------------- down-projection (gate): out = tanh(A @ W) ----------------
template <int D, bool TANH>
__global__ __launch_bounds__(256) void k_down(const float* __restrict__ A,
                                              const float* __restrict__ W,
                                              float* __restrict__ out) {
  constexpr int R = 256 / D;
  const int n = threadIdx.x % D;
  const int mi = threadIdx.x / D;
  const int m = blockIdx.x * R + mi;
  const float* a = A + (size_t)m * Cdim;
  float acc = 0.f;
  for (int k = 0; k < Cdim; k += 4) {
    float4 av = *reinterpret_cast<const float4*>(a + k);
    acc += av.x * W[(k + 0) * D + n];
    acc += av.y * W[(k + 1) * D + n];
    acc += av.z * W[(k + 2) * D + n];
    acc += av.w * W[(k + 3) * D + n];
  }
  out[(size_t)m * D + n] = TANH ? tanhf(acc) : acc;
}

// ---------------- merged LoRA downs: dec64(tanh) + aaa16 + ma16 + kkk16(tanh) + mk16 --
__global__ __launch_bounds__(256) void k_lora(
    const float* __restrict__ xwa, const float* __restrict__ xk,
    const float* __restrict__ dec_w1, const float* __restrict__ aaa_w1,
    const float* __restrict__ ma_w1, const float* __restrict__ kkk_w1,
    const float* __restrict__ mk_w1,
    float* __restrict__ d64, float* __restrict__ a16, float* __restrict__ m16,
    float* __restrict__ kkk16, float* __restrict__ mk16) {
  const int n = threadIdx.x & 127;
  const int mi = threadIdx.x >> 7;
  const int m = blockIdx.x * 2 + mi;
  const float* src; const float* W; int D; int nn; float* dst; bool act;
  if (n < 64)       { src = xwa; W = dec_w1; D = 64; nn = n;       dst = d64 + (size_t)m * 64;   act = true; }
  else if (n < 80)  { src = xwa; W = aaa_w1; D = 16; nn = n - 64;  dst = a16 + (size_t)m * 16;   act = false; }
  else if (n < 96)  { src = xwa; W = ma_w1;  D = 16; nn = n - 80;  dst = m16 + (size_t)m * 16;   act = false; }
  else if (n < 112) { src = xk;  W = kkk_w1; D = 16; nn = n - 96;  dst = kkk16 + (size_t)m * 16; act = true; }
  else              { src = xk;  W = mk_w1;  D = 16; nn = n - 112; dst = mk16 + (size_t)m * 16;  act = false; }
  const float* a = src + (size_t)m * Cdim;
  float acc = 0.f;
  for (int k = 0; k < Cdim; k += 4) {
    float4 av = *reinterpret_cast<const float4*>(a + k);
    acc += av.x * W[(k + 0) * D + nn];
    acc += av.y * W[(k + 1) * D + nn];
    acc += av.z * W[(k + 2) * D + nn];
    acc += av.w * W[(k + 3) * D + nn];
  }
  dst[nn] = act ? tanhf(acc) : acc;
}

// ---------------- mix-up: 4 planes -> xrg/xwa/xk fp32 + xrg/xk/xv bf16 ----------------
__global__ __launch_bounds__(256) void k_mixup(
    const float* __restrict__ x, const float* __restrict__ mixin,
    const float* __restrict__ w2,
    const float* __restrict__ brg_w, const float* __restrict__ bwa_w,
    const float* __restrict__ bk_w, const float* __restrict__ bv_w,
    float* __restrict__ xrg, float* __restrict__ xwa, float* __restrict__ xk,
    ushort_t* __restrict__ xrg_bf, ushort_t* __restrict__ xk_bf,
    ushort_t* __restrict__ xv_bf) {
  constexpr int R = 8;
  __shared__ float smix[R][128];
  const int m0 = blockIdx.x * R;
  for (int idx = threadIdx.x; idx < R * 128; idx += 256)
    smix[idx >> 7][idx & 127] = mixin[(size_t)(m0 + (idx >> 7)) * 128 + (idx & 127)];
  __syncthreads();
  for (int cc = 0; cc < 4; ++cc) {
    const int c = cc * 256 + threadIdx.x;
    float acc0[R] = {}, acc1[R] = {}, acc2[R] = {}, acc3[R] = {};
    for (int d = 0; d < 32; ++d) {
      float w0 = w2[(0 * 32 + d) * Cdim + c];
      float w1 = w2[(1 * 32 + d) * Cdim + c];
      float w2v = w2[(2 * 32 + d) * Cdim + c];
      float w3 = w2[(3 * 32 + d) * Cdim + c];
#pragma unroll
      for (int mi = 0; mi < R; ++mi) {
        acc0[mi] += smix[mi][d] * w0;
        acc1[mi] += smix[mi][32 + d] * w1;
        acc2[mi] += smix[mi][64 + d] * w2v;
        acc3[mi] += smix[mi][96 + d] * w3;
      }
    }
    float brg = brg_w[c], bwa = bwa_w[c], bk = bk_w[c], bv = bv_w[c];
#pragma unroll
    for (int mi = 0; mi < R; ++mi) {
      int m = m0 + mi;
      size_t id = (size_t)m * Cdim + c;
      float xvv = x[id];
      float xp = ((m & (Tn - 1)) == 0) ? 0.f : x[id - Cdim];
      float xx = xp - xvv;
      float vrg = xvv + xx * (brg + acc0[mi]);
      float vwa = xvv + xx * (bwa + acc1[mi]);
      float vk = xvv + xx * (bk + acc2[mi]);
      float vv = xvv + xx * (bv + acc3[mi]);
      xrg[id] = vrg;
      xwa[id] = vwa;
      xk[id] = vk;
      xrg_bf[id] = f2bf(vrg);
      xk_bf[id] = f2bf(vk);
      xv_bf[id] = f2bf(vv);
    }
  }
}

// ---------------- bf16 MFMA GEMM: 128x64 tile (512 blocks -> 2/CU co-residency) -------
__global__ __launch_bounds__(256) void k_gemm_mfma(
    const ushort_t* __restrict__ A, const ushort_t* __restrict__ Bw,
    float* __restrict__ C, int M, int Ncols, int K) {
  __shared__ ushort_t sh[24576];  // 2 bufs x (A 8192 + B 4096) ushorts = 48 KiB
  const int tid = threadIdx.x;
  const int lane = tid & 63;
  const int wave = tid >> 6;
  const int wr = wave >> 1, wc = wave & 1;   // 2x2 waves: 64x32 per wave
  const int m0 = blockIdx.x * 128, n0 = blockIdx.y * 64;
  const int NT = K >> 6;
  const ushort_t* gA = A + (size_t)m0 * K;
  const ushort_t* gB = Bw + (size_t)n0 * K;
  const int srow = lane >> 3;
  const int kbs = (lane & 7) ^ (srow & 7);   // inverse-swizzled source chunk

  f32x4 acc[4][2];
#pragma unroll
  for (int m = 0; m < 4; ++m)
#pragma unroll
    for (int n = 0; n < 2; ++n) acc[m][n] = (f32x4){0.f, 0.f, 0.f, 0.f};

  auto stage = [&](int buf, int k0) {
    ushort_t* LA = sh + buf * 12288;
    ushort_t* LB = LA + 8192;
#pragma unroll
    for (int q = 0; q < 4; ++q) {
      int row = wave * 32 + q * 8 + srow;
      gl_lds16(gA + (size_t)row * K + k0 + kbs * 8, LA + (wave * 4 + q) * 512);
    }
#pragma unroll
    for (int q = 0; q < 2; ++q) {
      int row = wave * 16 + q * 8 + srow;
      gl_lds16(gB + (size_t)row * K + k0 + kbs * 8, LB + (wave * 2 + q) * 512);
    }
  };

  auto compute = [&](int buf) {
    const ushort_t* LA = sh + buf * 12288;
    const ushort_t* LB = LA + 8192;
    const int r15 = lane & 15;
    const int kq = lane >> 4;
    const int rx = lane & 7;
#pragma unroll
    for (int kh = 0; kh < 2; ++kh) {
      bf16x8 af[4], bfr[2];
      const int kbsw = ((kh * 4 + kq) ^ rx) << 3;
#pragma unroll
      for (int m = 0; m < 4; ++m) {
        int row = wr * 64 + m * 16 + r15;
        af[m] = *reinterpret_cast<const bf16x8*>(&LA[row * 64 + kbsw]);
      }
#pragma unroll
      for (int n = 0; n < 2; ++n) {
        int col = wc * 32 + n * 16 + r15;
        bfr[n] = *reinterpret_cast<const bf16x8*>(&LB[col * 64 + kbsw]);
      }
#pragma unroll
      for (int m = 0; m < 4; ++m)
#pragma unroll
        for (int n = 0; n < 2; ++n)
          acc[m][n] = __builtin_amdgcn_mfma_f32_16x16x32_bf16(af[m], bfr[n], acc[m][n], 0, 0, 0);
    }
  };

  stage(0, 0);
  __syncthreads();
  for (int t = 0; t < NT; ++t) {
    int cur = t & 1;
    if (t + 1 < NT) stage(cur ^ 1, (t + 1) << 6);
    compute(cur);
    __syncthreads();
  }

  const int r15 = lane & 15, rq = lane >> 4;
#pragma unroll
  for (int m = 0; m < 4; ++m) {
    int row = m0 + wr * 64 + m * 16 + rq * 4;
#pragma unroll
    for (int n = 0; n < 2; ++n) {
      int col = n0 + wc * 32 + n * 16 + r15;
#pragma unroll
      for (int j = 0; j < 4; ++j)
        C[(size_t)(row + j) * Ncols + col] = acc[m][n][j];
    }
  }
}

// ---------------- up-projection (gate) ----------------
template <int D>
__global__ __launch_bounds__(256) void k_up(const float* __restrict__ MID,
                                            const float* __restrict__ W2,
                                            float* __restrict__ out) {
  constexpr int R = 8;
  __shared__ float sm[R][D];
  const int m0 = blockIdx.x * R;
  for (int idx = threadIdx.x; idx < R * D; idx += 256)
    sm[idx / D][idx % D] = MID[(size_t)(m0 + idx / D) * D + (idx % D)];
  __syncthreads();
  for (int cc = 0; cc < 4; ++cc) {
    const int c = cc * 256 + threadIdx.x;
    float acc[R] = {};
    for (int d = 0; d < D; ++d) {
      float wv = W2[(size_t)d * Cdim + c];
#pragma unroll
      for (int mi = 0; mi < R; ++mi) acc[mi] += sm[mi][d] * wv;
    }
#pragma unroll
    for (int mi = 0; mi < R; ++mi)
      out[(size_t)(m0 + mi) * Cdim + c] = acc[mi];
  }
}

// ---------------- combine: decay-up fused + kk-norm + a/ma/mk2 + k-mod + scan precompute
__global__ __launch_bounds__(256) void k_combine(
    float* __restrict__ kbuf,
    const float* __restrict__ d64, const float* __restrict__ dec_w2,
    const float* __restrict__ tdecay,
    const float* __restrict__ a16, const float* __restrict__ m16,
    const float* __restrict__ mk16, const float* __restrict__ kkk16,
    const float* __restrict__ aaa_w2, const float* __restrict__ ma_w2,
    const float* __restrict__ mk_w2, const float* __restrict__ kkk_w2,
    const float* __restrict__ aaaaa, const float* __restrict__ misc_a,
    const float* __restrict__ misc_k,
    float* __restrict__ kkout, float* __restrict__ bout,
    float* __restrict__ wexp) {
  const int bt = blockIdx.x >> 2;
  const int h = ((blockIdx.x & 3) << 2) + (threadIdx.x >> 6);
  const int lane = threadIdx.x & 63;
  const int c = h * 64 + lane;
  const size_t idx = (size_t)bt * Cdim + c;
  const float* A16 = a16 + bt * 16;
  const float* M16 = m16 + bt * 16;
  const float* K16 = mk16 + bt * 16;
  const float* KK16 = kkk16 + bt * 16;
  const float* D64 = d64 + bt * 64;
  float accA = 0, accM = 0, accK = 0, accKK = 0;
#pragma unroll
  for (int d = 0; d < 16; ++d) {
    accA += A16[d] * aaa_w2[d * Cdim + c];
    accM += M16[d] * ma_w2[d * Cdim + c];
    accK += K16[d] * mk_w2[d * Cdim + c];
    accKK += KK16[d] * kkk_w2[d * Cdim + c];
  }
  float accD = 0;
#pragma unroll 8
  for (int d = 0; d < 64; ++d) accD += D64[d] * dec_w2[d * Cdim + c];
  float z = tdecay[c] + accD;
  float wv = -log1pf(expf(-z)) - 0.5f;  // -softplus(-z)-0.5
  float kval = kbuf[idx];
  float kkraw = kval + accKK;
  float ss = kkraw * kkraw;
#pragma unroll
  for (int off = 32; off; off >>= 1) ss += __shfl_xor(ss, off, 64);
  float inv = 1.f / fmaxf(sqrtf(ss), 1e-12f);
  float kkn = kkraw * inv;
  float av = sigmoidf_(aaaaa[c] + accA);
  float mav = sigmoidf_(misc_a[c] + accM);
  float mkv = sigmoidf_(misc_k[c] + accK);
  float kn = (kval * mav + kval * av * (1.f - mav)) * expf(fminf(wv * mkv, 0.f));
  kbuf[idx] = kn;
  kkout[idx] = kkn;
  bout[idx] = kkn * av;
  wexp[idx] = expf(wv);
}

// ---------------- wkv7 scan v3: 2 rows/lane, all-DPP reduces, chunked LDS -------------
// 128 blocks = (b,h,half); 128 threads (2 waves). Lane: jc=tid&7 (8-wide j slice),
// rowslot=tid>>3 (16 slots) -> rows iA=half*32+rs, iB=iA+16. State 16 f32/lane.
// 8-lane reduce via DPP butterfly {xor1, xor2, xor7}: all VALU, no LDS shuffles.
__global__ __launch_bounds__(128) void k_scan(
    const float* __restrict__ r, const float* __restrict__ wexp,
    const float* __restrict__ k, const float* __restrict__ kk,
    const float* __restrict__ bb, const float* __restrict__ v,
    float* __restrict__ y) {
  __shared__ float lds[2][6][16][64];  // 48 KiB
  const int bh = blockIdx.x >> 1;
  const int half = blockIdx.x & 1;
  const int b = bh >> 4, h = bh & 15;
  const int tid = threadIdx.x;
  const int jc = tid & 7;
  const int j0 = jc * 8;
  const int rs = tid >> 3;               // 0..15
  const int iA = half * 32 + rs;
  const int iB = iA + 16;

  // staging coords: thread loads (step=tid>>3, j=(tid&7)*8): 2 float4 per array
  const int s_step = tid >> 3;
  const int s_j = (tid & 7) * 8;
  const size_t srcbase = (size_t)b * Tn * Cdim + h * 64 + s_j;
  const size_t ybase = (size_t)b * Tn * Cdim + h * 64;

  float sA[8] = {}, sB[8] = {};
  float4 g0a, g0b, g1a, g1b, g2a, g2b, g3a, g3b, g4a, g4b, g5a, g5b;

#define LOADC(c_) {                                                    \
    size_t o = srcbase + (size_t)((c_) * 16 + s_step) * Cdim;          \
    g0a = *reinterpret_cast<const float4*>(r + o);                     \
    g0b = *reinterpret_cast<const float4*>(r + o + 4);                 \
    g1a = *reinterpret_cast<const float4*>(wexp + o);                  \
    g1b = *reinterpret_cast<const float4*>(wexp + o + 4);              \
    g2a = *reinterpret_cast<const float4*>(k + o);                     \
    g2b = *reinterpret_cast<const float4*>(k + o + 4);                 \
    g3a = *reinterpret_cast<const float4*>(kk + o);                    \
    g3b = *reinterpret_cast<const float4*>(kk + o + 4);                \
    g4a = *reinterpret_cast<const float4*>(bb + o);                    \
    g4b = *reinterpret_cast<const float4*>(bb + o + 4);                \
    g5a = *reinterpret_cast<const float4*>(v + o);                     \
    g5b = *reinterpret_cast<const float4*>(v + o + 4);                 \
  }
#define WRITEC(bi_) {                                                  \
    *reinterpret_cast<float4*>(&lds[bi_][0][s_step][s_j]) = g0a;       \
    *reinterpret_cast<float4*>(&lds[bi_][0][s_step][s_j + 4]) = g0b;   \
    *reinterpret_cast<float4*>(&lds[bi_][1][s_step][s_j]) = g1a;       \
    *reinterpret_cast<float4*>(&lds[bi_][1][s_step][s_j + 4]) = g1b;   \
    *reinterpret_cast<float4*>(&lds[bi_][2][s_step][s_j]) = g2a;       \
    *reinterpret_cast<float4*>(&lds[bi_][2][s_step][s_j + 4]) = g2b;   \
    *reinterpret_cast<float4*>(&lds[bi_][3][s_step][s_j]) = g3a;       \
    *reinterpret_cast<float4*>(&lds[bi_][3][s_step][s_j + 4]) = g3b;   \
    *reinterpret_cast<float4*>(&lds[bi_][4][s_step][s_j]) = g4a;       \
    *reinterpret_cast<float4*>(&lds[bi_][4][s_step][s_j + 4]) = g4b;   \
    *reinterpret_cast<float4*>(&lds[bi_][5][s_step][s_j]) = g5a;       \
    *reinterpret_cast<float4*>(&lds[bi_][5][s_step][s_j + 4]) = g5b;   \
  }

  LOADC(0);
  WRITEC(0);
  __syncthreads();

  for (int c = 0; c < Tn / 16; ++c) {
    const int cur = c & 1;
    if (c + 1 < Tn / 16) LOADC(c + 1);
    const float(*Lc)[16][64] = lds[cur];
    const int c16 = c * 16;
#pragma unroll
    for (int s = 0; s < 16; ++s) {
      const float4 R0 = *reinterpret_cast<const float4*>(&Lc[0][s][j0]);
      const float4 R1 = *reinterpret_cast<const float4*>(&Lc[0][s][j0 + 4]);
      const float4 W0 = *reinterpret_cast<const float4*>(&Lc[1][s][j0]);
      const float4 W1 = *reinterpret_cast<const float4*>(&Lc[1][s][j0 + 4]);
      const float4 K0 = *reinterpret_cast<const float4*>(&Lc[2][s][j0]);
      const float4 K1 = *reinterpret_cast<const float4*>(&Lc[2][s][j0 + 4]);
      const float4 A0 = *reinterpret_cast<const float4*>(&Lc[3][s][j0]);
      const float4 A1 = *reinterpret_cast<const float4*>(&Lc[3][s][j0 + 4]);
      const float4 B0 = *reinterpret_cast<const float4*>(&Lc[4][s][j0]);
      const float4 B1 = *reinterpret_cast<const float4*>(&Lc[4][s][j0 + 4]);
      const float vA = Lc[5][s][iA];
      const float vB = Lc[5][s][iB];
      // partial dots with kk
      float pA = sA[0] * A0.x + sA[1] * A0.y + sA[2] * A0.z + sA[3] * A0.w
               + sA[4] * A1.x + sA[5] * A1.y + sA[6] * A1.z + sA[7] * A1.w;
      float pB = sB[0] * A0.x + sB[1] * A0.y + sB[2] * A0.z + sB[3] * A0.w
               + sB[4] * A1.x + sB[5] * A1.y + sB[6] * A1.z + sB[7] * A1.w;
      pA = dppadd<0xB1>(pA);  pB = dppadd<0xB1>(pB);    // xor1
      pA = dppadd<0x4E>(pA);  pB = dppadd<0x4E>(pB);    // xor2
      pA = dppadd<0x141>(pA); pB = dppadd<0x141>(pB);   // xor7 (half mirror)
      // state update: s = s*w + (v*k - p*b)   [a_t = -kk folded into sign]
      sA[0] = sA[0] * W0.x + (vA * K0.x - pA * B0.x);
      sA[1] = sA[1] * W0.y + (vA * K0.y - pA * B0.y);
      sA[2] = sA[2] * W0.z + (vA * K0.z - pA * B0.z);
      sA[3] = sA[3] * W0.w + (vA * K0.w - pA * B0.w);
      sA[4] = sA[4] * W1.x + (vA * K1.x - pA * B1.x);
      sA[5] = sA[5] * W1.y + (vA * K1.y - pA * B1.y);
      sA[6] = sA[6] * W1.z + (vA * K1.z - pA * B1.z);
      sA[7] = sA[7] * W1.w + (vA * K1.w - pA * B1.w);
      sB[0] = sB[0] * W0.x + (vB * K0.x - pB * B0.x);
      sB[1] = sB[1] * W0.y + (vB * K0.y - pB * B0.y);
      sB[2] = sB[2] * W0.z + (vB * K0.z - pB * B0.z);
      sB[3] = sB[3] * W0.w + (vB * K0.w - pB * B0.w);
      sB[4] = sB[4] * W1.x + (vB * K1.x - pB * B1.x);
      sB[5] = sB[5] * W1.y + (vB * K1.y - pB * B1.y);
      sB[6] = sB[6] * W1.z + (vB * K1.z - pB * B1.z);
      sB[7] = sB[7] * W1.w + (vB * K1.w - pB * B1.w);
      float yA = sA[0] * R0.x + sA[1] * R0.y + sA[2] * R0.z + sA[3] * R0.w
               + sA[4] * R1.x + sA[5] * R1.y + sA[6] * R1.z + sA[7] * R1.w;
      float yB = sB[0] * R0.x + sB[1] * R0.y + sB[2] * R0.z + sB[3] * R0.w
               + sB[4] * R1.x + sB[5] * R1.y + sB[6] * R1.z + sB[7] * R1.w;
      yA = dppadd<0xB1>(yA);  yB = dppadd<0xB1>(yB);
      yA = dppadd<0x4E>(yA);  yB = dppadd<0x4E>(yB);
      yA = dppadd<0x141>(yA); yB = dppadd<0x141>(yB);
      if (jc == 0) {
        y[ybase + (size_t)(c16 + s) * Cdim + iA] = yA;
        y[ybase + (size_t)(c16 + s) * Cdim + iB] = yB;
      }
    }
    if (c + 1 < Tn / 16) WRITEC((c + 1) & 1);
    __syncthreads();
  }
#undef LOADC
#undef WRITEC
}

// ---------------- GroupNorm + bonus + gate -> bf16 (input of out-GEMM) ----------------
__global__ __launch_bounds__(256) void k_gnout(
    const float* __restrict__ y, const float* __restrict__ r,
    const float* __restrict__ k, const float* __restrict__ v,
    const float* __restrict__ g, const float* __restrict__ faaaa,
    const float* __restrict__ lnw, const float* __restrict__ lnb,
    ushort_t* __restrict__ out_bf) {
  const int bt = blockIdx.x >> 2;
  const int h = ((blockIdx.x & 3) << 2) + (threadIdx.x >> 6);
  const int lane = threadIdx.x & 63;
  const int c = h * 64 + lane;
  const size_t idx = (size_t)bt * Cdim + c;
  float yv = y[idx];
  float mu = yv;
#pragma unroll
  for (int off = 32; off; off >>= 1) mu += __shfl_xor(mu, off, 64);
  mu *= (1.f / 64.f);
  float dv = yv - mu;
  float var = dv * dv;
#pragma unroll
  for (int off = 32; off; off >>= 1) var += __shfl_xor(var, off, 64);
  var *= (1.f / 64.f);
  float ynorm = dv * rsqrtf(var + 6.4e-4f) * lnw[c] + lnb[c];
  float rv = r[idx], kv = k[idx], vv = v[idx];
  float psum = rv * kv * faaaa[c];
#pragma unroll
  for (int off = 32; off; off >>= 1) psum += __shfl_xor(psum, off, 64);
  out_bf[idx] = f2bf((ynorm + psum * vv) * g[idx]);
}

extern "C" void kernel_launch(void* const* d_in, const int* in_sizes, int n_in,
                              void* d_out, int out_size, void* d_ws, size_t ws_size,
                              hipStream_t stream) {
  (void)in_sizes; (void)n_in; (void)out_size; (void)ws_size;
  const float* x = (const float*)d_in[0];
  const float* maa_x = (const float*)d_in[1];
  const float* maa_rg = (const float*)d_in[2];
  const float* maa_wa = (const float*)d_in[3];
  const float* maa_k = (const float*)d_in[4];
  const float* maa_v = (const float*)d_in[5];
  const float* maa_w1 = (const float*)d_in[6];
  const float* maa_w2 = (const float*)d_in[7];
  const float* tdecay = (const float*)d_in[8];
  const float* dec_w1 = (const float*)d_in[9];
  const float* dec_w2 = (const float*)d_in[10];
  const float* faaaa = (const float*)d_in[11];
  const float* aaaaa = (const float*)d_in[12];
  const float* aaa_w1 = (const float*)d_in[13];
  const float* aaa_w2 = (const float*)d_in[14];
  const float* kkk_w1 = (const float*)d_in[15];
  const float* kkk_w2 = (const float*)d_in[16];
  const float* gate_w1 = (const float*)d_in[17];
  const float* gate_w2 = (const float*)d_in[18];
  const float* ma_w1 = (const float*)d_in[19];
  const float* ma_w2 = (const float*)d_in[20];
  const float* misc_a = (const float*)d_in[21];
  const float* mk_w1 = (const float*)d_in[22];
  const float* mk_w2 = (const float*)d_in[23];
  const float* misc_k = (const float*)d_in[24];
  const float* w_r = (const float*)d_in[25];
  const float* w_k = (const float*)d_in[26];
  const float* w_v = (const float*)d_in[27];
  const float* w_o = (const float*)d_in[28];
  const float* lnw = (const float*)d_in[29];
  const float* lnb = (const float*)d_in[30];
  float* out = (float*)d_out;

  float* ws = (float*)d_ws;
  const size_t F = (size_t)BT * Cdim;  // 4M elements
  float* xrg = ws + 0 * F;             // fp32 xrg; later gate-up output g
  float* xwa = ws + 1 * F;             // fp32 xwa; later y
  float* xk = ws + 2 * F;              // fp32 xk
  float* wexp = ws + 3 * F;            // exp(decay) for scan
  float* rb = ws + 4 * F;              // r
  float* kb = ws + 5 * F;
  float* vb = ws + 6 * F;
  float* kkb = ws + 7 * F;
  float* ab = ws + 8 * F;              // b = kk*a
  float* smalls = ws + 9 * F;
  float* mixin = smalls;                   // BT*128
  float* g128 = mixin + (size_t)BT * 128;  // BT*128
  float* d64 = g128 + (size_t)BT * 128;    // BT*64
  float* a16 = d64 + (size_t)BT * 64;      // BT*16
  float* m16 = a16 + (size_t)BT * 16;
  float* mk16 = m16 + (size_t)BT * 16;
  float* kkk16 = mk16 + (size_t)BT * 16;

  ushort_t* ub = (ushort_t*)(kkk16 + (size_t)BT * 16);
  ushort_t* xrg_bf = ub + 0 * F;
  ushort_t* xk_bf = ub + 1 * F;
  ushort_t* xv_bf = ub + 2 * F;
  ushort_t* yg_bf = ub + 3 * F;
  ushort_t* wr_bf = ub + 4 * F;
  ushort_t* wk_bf = wr_bf + (size_t)Cdim * Cdim;
  ushort_t* wv_bf = wk_bf + (size_t)Cdim * Cdim;
  ushort_t* wo_bf = wv_bf + (size_t)Cdim * Cdim;

  dim3 blk(256);
  dim3 ggrid(BT / 128, Cdim / 64);  // 32 x 16 = 512 blocks

  // 0. weight conversions (one launch)
  k_f2bf4<<<4096, blk, 0, stream>>>(w_r, w_k, w_v, w_o, wr_bf, wk_bf, wv_bf, wo_bf);
  // 1. fused xmix + mixin down
  k_mixdown<<<BT / 2, blk, 0, stream>>>(x, maa_x, maa_w1, mixin);
  // 2. mix-up
  k_mixup<<<BT / 8, blk, 0, stream>>>(x, mixin, maa_w2, maa_rg, maa_wa, maa_k, maa_v,
                                      xrg, xwa, xk, xrg_bf, xk_bf, xv_bf);
  // 3. gate down
  k_down<128, true><<<BT / 2, blk, 0, stream>>>(xrg, gate_w1, g128);
  // 4-6. big GEMMs (bf16 MFMA)
  k_gemm_mfma<<<ggrid, blk, 0, stream>>>(xrg_bf, wr_bf, rb, BT, Cdim, Cdim);
  k_gemm_mfma<<<ggrid, blk, 0, stream>>>(xk_bf, wk_bf, kb, BT, Cdim, Cdim);
  k_gemm_mfma<<<ggrid, blk, 0, stream>>>(xv_bf, wv_bf, vb, BT, Cdim, Cdim);
  // 7. merged LoRA downs
  k_lora<<<BT / 2, blk, 0, stream>>>(xwa, xk, dec_w1, aaa_w1, ma_w1, kkk_w1, mk_w1,
                                     d64, a16, m16, kkk16, mk16);
  // 8. gate up -> xrg slot
  k_up<128><<<BT / 8, blk, 0, stream>>>(g128, gate_w2, xrg);
  // 9. combine (decay-up fused; wexp; b = kk*a)
  k_combine<<<BT * 4, blk, 0, stream>>>(kb, d64, dec_w2, tdecay,
                                        a16, m16, mk16, kkk16,
                                        aaa_w2, ma_w2, mk_w2, kkk_w2,
                                        aaaaa, misc_a, misc_k, kkb, ab, wexp);
  // 10. wkv7 scan v3 -> y (xwa slot)
  k_scan<<<128, dim3(128), 0, stream>>>(rb, wexp, kb, kkb, ab, vb, xwa);
  // 11. GN + bonus + gate -> yg_bf
  k_gnout<<<BT * 4, blk, 0, stream>>>(xwa, rb, kb, vb, xrg, faaaa, lnw, lnb, yg_bf);
  // 12. output GEMM -> d_out
  k_gemm_mfma<<<ggrid, blk, 0, stream>>>(yg_bf, wo_bf, out, BT, Cdim, Cdim);
}

// Round 6
// 961.430 us; speedup vs baseline: 1.8479x; 1.3196x over previous
//
#include <hip/hip_runtime.h>
#include <math.h>

#define BT   4096
#define Cdim 1024
#define Hn   16
#define Tn   1024

typedef unsigned short ushort_t;
typedef short bf16x8 __attribute__((ext_vector_type(8)));
typedef float f32x4 __attribute__((ext_vector_type(4)));

static __device__ __forceinline__ float sigmoidf_(float z) { return 1.f / (1.f + expf(-z)); }

static __device__ __forceinline__ ushort_t f2bf(float f) {  // RNE fp32->bf16
  unsigned int u = __float_as_uint(f);
  u += 0x7fffu + ((u >> 16) & 1u);
  return (ushort_t)(u >> 16);
}

static __device__ __forceinline__ void gl_lds16(const ushort_t* g, ushort_t* l) {
  __builtin_amdgcn_global_load_lds(
      (const __attribute__((address_space(1))) unsigned int*)g,
      (__attribute__((address_space(3))) unsigned int*)l, 16, 0, 0);
}

// DPP cross-lane add. 0xB1=xor1(quad), 0x4E=xor2(quad), 0x141=ROW_HALF_MIRROR(xor7)
template <int CTRL>
static __device__ __forceinline__ float dppadd(float x) {
  int t = __builtin_amdgcn_mov_dpp(__float_as_int(x), CTRL, 0xF, 0xF, true);
  return x + __int_as_float(t);
}

// ---------------- fp32 -> bf16: 4 big weight matrices ----------------
__global__ __launch_bounds__(256) void k_f2bf4(
    const float* __restrict__ w0, const float* __restrict__ w1,
    const float* __restrict__ w2, const float* __restrict__ w3,
    ushort_t* __restrict__ o0, ushort_t* __restrict__ o1,
    ushort_t* __restrict__ o2, ushort_t* __restrict__ o3) {
  int idx4 = blockIdx.x * 256 + threadIdx.x;
  int which = idx4 >> 18;
  int loc = (idx4 & 0x3FFFF) * 4;
  const float* in = which == 0 ? w0 : which == 1 ? w1 : which == 2 ? w2 : w3;
  ushort_t* out = which == 0 ? o0 : which == 1 ? o1 : which == 2 ? o2 : o3;
  float4 v = *reinterpret_cast<const float4*>(in + loc);
  ushort4 o;
  o.x = f2bf(v.x); o.y = f2bf(v.y); o.z = f2bf(v.z); o.w = f2bf(v.w);
  *reinterpret_cast<ushort4*>(out + loc) = o;
}

// ---------------- prep: transposed bf16 weight panels (n,k layout for GEMM B) --------
// n-space 0..447: [0,128)=maa_w1^T | [128,256)=gate_w1^T | [256,384)=[dec|aaa|ma|0]^T
// | [384,448)=[kkk|mk|0]^T
__global__ __launch_bounds__(256) void k_prepw(
    const float* __restrict__ maa_w1, const float* __restrict__ gate_w1,
    const float* __restrict__ dec_w1, const float* __restrict__ aaa_w1,
    const float* __restrict__ ma_w1, const float* __restrict__ kkk_w1,
    const float* __restrict__ mk_w1,
    ushort_t* __restrict__ Tmaa, ushort_t* __restrict__ Tgate,
    ushort_t* __restrict__ Twa, ushort_t* __restrict__ Tk) {
  __shared__ float tile[64][65];
  const int k0 = blockIdx.x * 64, n0 = blockIdx.y * 64;
  for (int i = threadIdx.x; i < 64 * 64; i += 256) {
    int kk_ = i >> 6, nn = i & 63;
    int k = k0 + kk_, n = n0 + nn;
    float v = 0.f;
    if (n < 128) v = maa_w1[k * 128 + n];
    else if (n < 256) v = gate_w1[k * 128 + (n - 128)];
    else if (n < 384) {
      int m = n - 256;
      if (m < 64) v = dec_w1[k * 64 + m];
      else if (m < 80) v = aaa_w1[k * 16 + m - 64];
      else if (m < 96) v = ma_w1[k * 16 + m - 80];
    } else {
      int m = n - 384;
      if (m < 16) v = kkk_w1[k * 16 + m];
      else if (m < 32) v = mk_w1[k * 16 + m - 16];
    }
    tile[kk_][nn] = v;
  }
  __syncthreads();
  for (int i = threadIdx.x; i < 64 * 64; i += 256) {
    int nn = i >> 6, kk_ = i & 63;
    int n = n0 + nn, k = k0 + kk_;
    ushort_t bv = f2bf(tile[kk_][nn]);
    if (n < 128) Tmaa[n * 1024 + k] = bv;
    else if (n < 256) Tgate[(n - 128) * 1024 + k] = bv;
    else if (n < 384) Twa[(n - 256) * 1024 + k] = bv;
    else Tk[(n - 384) * 1024 + k] = bv;
  }
}

// ---------------- xmix -> bf16 ----------------
__global__ __launch_bounds__(256) void k_xmix(const float* __restrict__ x,
                                              const float* __restrict__ maa_x,
                                              ushort_t* __restrict__ out_bf) {
  int idx = blockIdx.x * 256 + threadIdx.x;
  int c = idx & (Cdim - 1);
  int bt = idx >> 10;
  float xv = x[idx];
  float xp = ((bt & (Tn - 1)) == 0) ? 0.f : x[idx - Cdim];
  out_bf[idx] = f2bf(xv + (xp - xv) * maa_x[c]);
}

// ---------------- mix-up: tanh(mixin_raw) lora -> 4 bf16 planes ----------------
__global__ __launch_bounds__(256) void k_mixup(
    const float* __restrict__ x, const float* __restrict__ mixin_raw,
    const float* __restrict__ w2,
    const float* __restrict__ brg_w, const float* __restrict__ bwa_w,
    const float* __restrict__ bk_w, const float* __restrict__ bv_w,
    ushort_t* __restrict__ xrg_bf, ushort_t* __restrict__ xwa_bf,
    ushort_t* __restrict__ xk_bf, ushort_t* __restrict__ xv_bf) {
  constexpr int R = 8;
  __shared__ float smix[R][128];
  const int m0 = blockIdx.x * R;
  for (int idx = threadIdx.x; idx < R * 128; idx += 256)
    smix[idx >> 7][idx & 127] =
        tanhf(mixin_raw[(size_t)(m0 + (idx >> 7)) * 128 + (idx & 127)]);
  __syncthreads();
  for (int cc = 0; cc < 4; ++cc) {
    const int c = cc * 256 + threadIdx.x;
    float acc0[R] = {}, acc1[R] = {}, acc2[R] = {}, acc3[R] = {};
    for (int d = 0; d < 32; ++d) {
      float w0 = w2[(0 * 32 + d) * Cdim + c];
      float w1 = w2[(1 * 32 + d) * Cdim + c];
      float w2v = w2[(2 * 32 + d) * Cdim + c];
      float w3 = w2[(3 * 32 + d) * Cdim + c];
#pragma unroll
      for (int mi = 0; mi < R; ++mi) {
        acc0[mi] += smix[mi][d] * w0;
        acc1[mi] += smix[mi][32 + d] * w1;
        acc2[mi] += smix[mi][64 + d] * w2v;
        acc3[mi] += smix[mi][96 + d] * w3;
      }
    }
    float brg = brg_w[c], bwa = bwa_w[c], bk = bk_w[c], bv = bv_w[c];
#pragma unroll
    for (int mi = 0; mi < R; ++mi) {
      int m = m0 + mi;
      size_t id = (size_t)m * Cdim + c;
      float xvv = x[id];
      float xp = ((m & (Tn - 1)) == 0) ? 0.f : x[id - Cdim];
      float xx = xp - xvv;
      xrg_bf[id] = f2bf(xvv + xx * (brg + acc0[mi]));
      xwa_bf[id] = f2bf(xvv + xx * (bwa + acc1[mi]));
      xk_bf[id] = f2bf(xvv + xx * (bk + acc2[mi]));
      xv_bf[id] = f2bf(xvv + xx * (bv + acc3[mi]));
    }
  }
}

// ---------------- bf16 MFMA GEMM: C[m,n] = sum_k A[m,k]*Bw[n,k]; 128x64 tile ----------
__global__ __launch_bounds__(256) void k_gemm_mfma(
    const ushort_t* __restrict__ A, const ushort_t* __restrict__ Bw,
    float* __restrict__ C, int M, int Ncols, int K) {
  __shared__ ushort_t sh[24576];
  const int tid = threadIdx.x;
  const int lane = tid & 63;
  const int wave = tid >> 6;
  const int wr = wave >> 1, wc = wave & 1;
  const int m0 = blockIdx.x * 128, n0 = blockIdx.y * 64;
  const int NT = K >> 6;
  const ushort_t* gA = A + (size_t)m0 * K;
  const ushort_t* gB = Bw + (size_t)n0 * K;
  const int srow = lane >> 3;
  const int kbs = (lane & 7) ^ (srow & 7);

  f32x4 acc[4][2];
#pragma unroll
  for (int m = 0; m < 4; ++m)
#pragma unroll
    for (int n = 0; n < 2; ++n) acc[m][n] = (f32x4){0.f, 0.f, 0.f, 0.f};

  auto stage = [&](int buf, int k0) {
    ushort_t* LA = sh + buf * 12288;
    ushort_t* LB = LA + 8192;
#pragma unroll
    for (int q = 0; q < 4; ++q) {
      int row = wave * 32 + q * 8 + srow;
      gl_lds16(gA + (size_t)row * K + k0 + kbs * 8, LA + (wave * 4 + q) * 512);
    }
#pragma unroll
    for (int q = 0; q < 2; ++q) {
      int row = wave * 16 + q * 8 + srow;
      gl_lds16(gB + (size_t)row * K + k0 + kbs * 8, LB + (wave * 2 + q) * 512);
    }
  };

  auto compute = [&](int buf) {
    const ushort_t* LA = sh + buf * 12288;
    const ushort_t* LB = LA + 8192;
    const int r15 = lane & 15;
    const int kq = lane >> 4;
    const int rx = lane & 7;
#pragma unroll
    for (int kh = 0; kh < 2; ++kh) {
      bf16x8 af[4], bfr[2];
      const int kbsw = ((kh * 4 + kq) ^ rx) << 3;
#pragma unroll
      for (int m = 0; m < 4; ++m) {
        int row = wr * 64 + m * 16 + r15;
        af[m] = *reinterpret_cast<const bf16x8*>(&LA[row * 64 + kbsw]);
      }
#pragma unroll
      for (int n = 0; n < 2; ++n) {
        int col = wc * 32 + n * 16 + r15;
        bfr[n] = *reinterpret_cast<const bf16x8*>(&LB[col * 64 + kbsw]);
      }
#pragma unroll
      for (int m = 0; m < 4; ++m)
#pragma unroll
        for (int n = 0; n < 2; ++n)
          acc[m][n] = __builtin_amdgcn_mfma_f32_16x16x32_bf16(af[m], bfr[n], acc[m][n], 0, 0, 0);
    }
  };

  stage(0, 0);
  __syncthreads();
  for (int t = 0; t < NT; ++t) {
    int cur = t & 1;
    if (t + 1 < NT) stage(cur ^ 1, (t + 1) << 6);
    compute(cur);
    __syncthreads();
  }

  const int r15 = lane & 15, rq = lane >> 4;
#pragma unroll
  for (int m = 0; m < 4; ++m) {
    int row = m0 + wr * 64 + m * 16 + rq * 4;
#pragma unroll
    for (int n = 0; n < 2; ++n) {
      int col = n0 + wc * 32 + n * 16 + r15;
#pragma unroll
      for (int j = 0; j < 4; ++j)
        C[(size_t)(row + j) * Ncols + col] = acc[m][n][j];
    }
  }
}

// ---------------- gate up: out = tanh(g_raw) @ gate_w2 ----------------
template <int D>
__global__ __launch_bounds__(256) void k_up(const float* __restrict__ MID,
                                            const float* __restrict__ W2,
                                            float* __restrict__ out) {
  constexpr int R = 8;
  __shared__ float sm[R][D];
  const int m0 = blockIdx.x * R;
  for (int idx = threadIdx.x; idx < R * D; idx += 256)
    sm[idx / D][idx % D] = tanhf(MID[(size_t)(m0 + idx / D) * D + (idx % D)]);
  __syncthreads();
  for (int cc = 0; cc < 4; ++cc) {
    const int c = cc * 256 + threadIdx.x;
    float acc[R] = {};
    for (int d = 0; d < D; ++d) {
      float wv = W2[(size_t)d * Cdim + c];
#pragma unroll
      for (int mi = 0; mi < R; ++mi) acc[mi] += sm[mi][d] * wv;
    }
#pragma unroll
    for (int mi = 0; mi < R; ++mi)
      out[(size_t)(m0 + mi) * Cdim + c] = acc[mi];
  }
}

// ---------------- combine v2: 5 LoRA-ups + kk-norm + k-mod + scan precompute ----------
// grid (4 hg, 256 btg); block 256 = 4 waves; wave w: bt rows bt0+w*4+{0..3};
// lane c = (hg*4+q)*64 + lane, q=0..3. mid staged in LDS (tanh on dec/kkk slices).
__global__ __launch_bounds__(256) void k_combine(
    float* __restrict__ kbuf,
    const float* __restrict__ wa_mid, const float* __restrict__ k_mid,
    const float* __restrict__ dec_w2, const float* __restrict__ aaa_w2,
    const float* __restrict__ ma_w2, const float* __restrict__ kkk_w2,
    const float* __restrict__ mk_w2,
    const float* __restrict__ tdecay, const float* __restrict__ aaaaa,
    const float* __restrict__ misc_a, const float* __restrict__ misc_k,
    float* __restrict__ kkout, float* __restrict__ bout,
    float* __restrict__ wexp) {
  __shared__ float mid[16][128];
  const int hg = blockIdx.x;
  const int bt0 = blockIdx.y * 16;
  const int tid = threadIdx.x;
  const int lane = tid & 63;
  const int btw = (tid >> 6) * 4;
  for (int i = tid; i < 16 * 128; i += 256) {
    int row = i >> 7, col = i & 127;
    float v;
    if (col < 96) v = wa_mid[(size_t)(bt0 + row) * 128 + col];
    else v = k_mid[(size_t)(bt0 + row) * 64 + (col - 96)];
    if (col < 64 || (col >= 96 && col < 112)) v = tanhf(v);
    mid[row][col] = v;
  }
  __syncthreads();

  int cq[4];
#pragma unroll
  for (int q = 0; q < 4; ++q) cq[q] = ((hg * 4 + q) << 6) + lane;

  float acc0[4][4] = {}, acc1[4][4] = {}, acc2[4][4] = {}, acc3[4][4] = {}, acc4[4][4] = {};

#define PASS(ACC, W2P, DBASE, NCH)                                        \
  _Pragma("unroll") for (int ch = 0; ch < NCH; ++ch) {                    \
    const int d0 = ch * 4;                                                \
    float4 m0 = *reinterpret_cast<const float4*>(&mid[btw + 0][DBASE + d0]); \
    float4 m1 = *reinterpret_cast<const float4*>(&mid[btw + 1][DBASE + d0]); \
    float4 m2 = *reinterpret_cast<const float4*>(&mid[btw + 2][DBASE + d0]); \
    float4 m3 = *reinterpret_cast<const float4*>(&mid[btw + 3][DBASE + d0]); \
    _Pragma("unroll") for (int q = 0; q < 4; ++q) {                       \
      const float w0 = W2P[(d0 + 0) * Cdim + cq[q]];                      \
      const float w1 = W2P[(d0 + 1) * Cdim + cq[q]];                      \
      const float w2v = W2P[(d0 + 2) * Cdim + cq[q]];                     \
      const float w3 = W2P[(d0 + 3) * Cdim + cq[q]];                      \
      ACC[0][q] += m0.x * w0 + m0.y * w1 + m0.z * w2v + m0.w * w3;        \
      ACC[1][q] += m1.x * w0 + m1.y * w1 + m1.z * w2v + m1.w * w3;        \
      ACC[2][q] += m2.x * w0 + m2.y * w1 + m2.z * w2v + m2.w * w3;        \
      ACC[3][q] += m3.x * w0 + m3.y * w1 + m3.z * w2v + m3.w * w3;        \
    }                                                                     \
  }

  PASS(acc0, dec_w2, 0, 16)
  PASS(acc1, aaa_w2, 64, 4)
  PASS(acc2, ma_w2, 80, 4)
  PASS(acc3, kkk_w2, 96, 4)
  PASS(acc4, mk_w2, 112, 4)
#undef PASS

#pragma unroll
  for (int bt = 0; bt < 4; ++bt) {
#pragma unroll
    for (int q = 0; q < 4; ++q) {
      const int c = cq[q];
      const size_t idx = (size_t)(bt0 + btw + bt) * Cdim + c;
      float kval = kbuf[idx];
      float kkraw = kval + acc3[bt][q];
      float ss = kkraw * kkraw;
#pragma unroll
      for (int off = 32; off; off >>= 1) ss += __shfl_xor(ss, off, 64);
      float kkn = kkraw / fmaxf(sqrtf(ss), 1e-12f);
      float av = sigmoidf_(aaaaa[c] + acc1[bt][q]);
      float mav = sigmoidf_(misc_a[c] + acc2[bt][q]);
      float mkv = sigmoidf_(misc_k[c] + acc4[bt][q]);
      float z = tdecay[c] + acc0[bt][q];
      float wv = -log1pf(expf(-z)) - 0.5f;
      float kn = (kval * mav + kval * av * (1.f - mav)) * expf(fminf(wv * mkv, 0.f));
      kbuf[idx] = kn;
      kkout[idx] = kkn;
      bout[idx] = kkn * av;
      wexp[idx] = expf(wv);
    }
  }
}

// ---------------- wkv7 scan v4: 1 wave/block, 256 blocks (all CUs) -------------------
// block = (b,h,quarter): 16 rows; lane: jc=lane&7 (8-wide j slice), rs=lane>>3;
// rows iA=q*16+rs, iB=iA+8 (2 rows/lane, 16 f32 state). DPP reduces, chunked dbuf LDS.
__global__ __launch_bounds__(64) void k_scan(
    const float* __restrict__ r, const float* __restrict__ wexp,
    const float* __restrict__ k, const float* __restrict__ kk,
    const float* __restrict__ bb, const float* __restrict__ v,
    float* __restrict__ y) {
  __shared__ float lds[2][6][16][64];  // 48 KiB
  const int q = blockIdx.x & 3;
  const int bh = blockIdx.x >> 2;
  const int b = bh >> 4, h = bh & 15;
  const int lane = threadIdx.x;
  const int jc = lane & 7;
  const int j0 = jc * 8;
  const int rs = lane >> 3;
  const int iA = q * 16 + rs, iB = iA + 8;
  const size_t sb = (size_t)b * Tn * Cdim + h * 64;

  float sA[8] = {}, sB[8] = {};
  float4 g[6][4];
  const float* srcs0 = r; const float* srcs1 = wexp; const float* srcs2 = k;
  const float* srcs3 = kk; const float* srcs4 = bb; const float* srcs5 = v;

#define LOAD1(ARR, PTR)                                                    \
  _Pragma("unroll") for (int rep = 0; rep < 4; ++rep) {                    \
    int flat = rep * 64 + lane;                                            \
    int step = flat >> 4;                                                  \
    int j4 = (flat & 15) * 4;                                              \
    g[ARR][rep] = *reinterpret_cast<const float4*>(                        \
        PTR + sb + (size_t)(cc * 16 + step) * Cdim + j4);                  \
  }
#define WRITE1(BI, ARR)                                                    \
  _Pragma("unroll") for (int rep = 0; rep < 4; ++rep) {                    \
    int flat = rep * 64 + lane;                                            \
    int step = flat >> 4;                                                  \
    int j4 = (flat & 15) * 4;                                              \
    *reinterpret_cast<float4*>(&lds[BI][ARR][step][j4]) = g[ARR][rep];     \
  }

  {
    const int cc = 0;
    LOAD1(0, srcs0) LOAD1(1, srcs1) LOAD1(2, srcs2)
    LOAD1(3, srcs3) LOAD1(4, srcs4) LOAD1(5, srcs5)
    WRITE1(0, 0) WRITE1(0, 1) WRITE1(0, 2) WRITE1(0, 3) WRITE1(0, 4) WRITE1(0, 5)
  }
  __syncthreads();

  for (int c = 0; c < Tn / 16; ++c) {
    const int cur = c & 1;
    if (c + 1 < Tn / 16) {
      const int cc = c + 1;
      LOAD1(0, srcs0) LOAD1(1, srcs1) LOAD1(2, srcs2)
      LOAD1(3, srcs3) LOAD1(4, srcs4) LOAD1(5, srcs5)
    }
    const float(*Lc)[16][64] = lds[cur];
    const int c16 = c * 16;
#pragma unroll
    for (int s = 0; s < 16; ++s) {
      const float4 R0 = *reinterpret_cast<const float4*>(&Lc[0][s][j0]);
      const float4 R1 = *reinterpret_cast<const float4*>(&Lc[0][s][j0 + 4]);
      const float4 W0 = *reinterpret_cast<const float4*>(&Lc[1][s][j0]);
      const float4 W1 = *reinterpret_cast<const float4*>(&Lc[1][s][j0 + 4]);
      const float4 K0 = *reinterpret_cast<const float4*>(&Lc[2][s][j0]);
      const float4 K1 = *reinterpret_cast<const float4*>(&Lc[2][s][j0 + 4]);
      const float4 A0 = *reinterpret_cast<const float4*>(&Lc[3][s][j0]);
      const float4 A1 = *reinterpret_cast<const float4*>(&Lc[3][s][j0 + 4]);
      const float4 B0 = *reinterpret_cast<const float4*>(&Lc[4][s][j0]);
      const float4 B1 = *reinterpret_cast<const float4*>(&Lc[4][s][j0 + 4]);
      const float vA = Lc[5][s][iA];
      const float vB = Lc[5][s][iB];
      float pA = sA[0] * A0.x + sA[1] * A0.y + sA[2] * A0.z + sA[3] * A0.w
               + sA[4] * A1.x + sA[5] * A1.y + sA[6] * A1.z + sA[7] * A1.w;
      float pB = sB[0] * A0.x + sB[1] * A0.y + sB[2] * A0.z + sB[3] * A0.w
               + sB[4] * A1.x + sB[5] * A1.y + sB[6] * A1.z + sB[7] * A1.w;
      pA = dppadd<0xB1>(pA);  pB = dppadd<0xB1>(pB);
      pA = dppadd<0x4E>(pA);  pB = dppadd<0x4E>(pB);
      pA = dppadd<0x141>(pA); pB = dppadd<0x141>(pB);
      sA[0] = sA[0] * W0.x + (vA * K0.x - pA * B0.x);
      sA[1] = sA[1] * W0.y + (vA * K0.y - pA * B0.y);
      sA[2] = sA[2] * W0.z + (vA * K0.z - pA * B0.z);
      sA[3] = sA[3] * W0.w + (vA * K0.w - pA * B0.w);
      sA[4] = sA[4] * W1.x + (vA * K1.x - pA * B1.x);
      sA[5] = sA[5] * W1.y + (vA * K1.y - pA * B1.y);
      sA[6] = sA[6] * W1.z + (vA * K1.z - pA * B1.z);
      sA[7] = sA[7] * W1.w + (vA * K1.w - pA * B1.w);
      sB[0] = sB[0] * W0.x + (vB * K0.x - pB * B0.x);
      sB[1] = sB[1] * W0.y + (vB * K0.y - pB * B0.y);
      sB[2] = sB[2] * W0.z + (vB * K0.z - pB * B0.z);
      sB[3] = sB[3] * W0.w + (vB * K0.w - pB * B0.w);
      sB[4] = sB[4] * W1.x + (vB * K1.x - pB * B1.x);
      sB[5] = sB[5] * W1.y + (vB * K1.y - pB * B1.y);
      sB[6] = sB[6] * W1.z + (vB * K1.z - pB * B1.z);
      sB[7] = sB[7] * W1.w + (vB * K1.w - pB * B1.w);
      float yA = sA[0] * R0.x + sA[1] * R0.y + sA[2] * R0.z + sA[3] * R0.w
               + sA[4] * R1.x + sA[5] * R1.y + sA[6] * R1.z + sA[7] * R1.w;
      float yB = sB[0] * R0.x + sB[1] * R0.y + sB[2] * R0.z + sB[3] * R0.w
               + sB[4] * R1.x + sB[5] * R1.y + sB[6] * R1.z + sB[7] * R1.w;
      yA = dppadd<0xB1>(yA);  yB = dppadd<0xB1>(yB);
      yA = dppadd<0x4E>(yA);  yB = dppadd<0x4E>(yB);
      yA = dppadd<0x141>(yA); yB = dppadd<0x141>(yB);
      if (jc == 0) {
        y[sb + (size_t)(c16 + s) * Cdim + iA] = yA;
        y[sb + (size_t)(c16 + s) * Cdim + iB] = yB;
      }
    }
    if (c + 1 < Tn / 16) {
      const int nb = (c + 1) & 1;
      WRITE1(nb, 0) WRITE1(nb, 1) WRITE1(nb, 2) WRITE1(nb, 3) WRITE1(nb, 4) WRITE1(nb, 5)
    }
    __syncthreads();
  }
#undef LOAD1
#undef WRITE1
}

// ---------------- GroupNorm + bonus + gate -> bf16 ----------------
__global__ __launch_bounds__(256) void k_gnout(
    const float* __restrict__ y, const float* __restrict__ r,
    const float* __restrict__ k, const float* __restrict__ v,
    const float* __restrict__ g, const float* __restrict__ faaaa,
    const float* __restrict__ lnw, const float* __restrict__ lnb,
    ushort_t* __restrict__ out_bf) {
  const int bt = blockIdx.x >> 2;
  const int h = ((blockIdx.x & 3) << 2) + (threadIdx.x >> 6);
  const int lane = threadIdx.x & 63;
  const int c = h * 64 + lane;
  const size_t idx = (size_t)bt * Cdim + c;
  float yv = y[idx];
  float mu = yv;
#pragma unroll
  for (int off = 32; off; off >>= 1) mu += __shfl_xor(mu, off, 64);
  mu *= (1.f / 64.f);
  float dv = yv - mu;
  float var = dv * dv;
#pragma unroll
  for (int off = 32; off; off >>= 1) var += __shfl_xor(var, off, 64);
  var *= (1.f / 64.f);
  float ynorm = dv * rsqrtf(var + 6.4e-4f) * lnw[c] + lnb[c];
  float rv = r[idx], kv = k[idx], vv = v[idx];
  float psum = rv * kv * faaaa[c];
#pragma unroll
  for (int off = 32; off; off >>= 1) psum += __shfl_xor(psum, off, 64);
  out_bf[idx] = f2bf((ynorm + psum * vv) * g[idx]);
}

extern "C" void kernel_launch(void* const* d_in, const int* in_sizes, int n_in,
                              void* d_out, int out_size, void* d_ws, size_t ws_size,
                              hipStream_t stream) {
  (void)in_sizes; (void)n_in; (void)out_size; (void)ws_size;
  const float* x = (const float*)d_in[0];
  const float* maa_x = (const float*)d_in[1];
  const float* maa_rg = (const float*)d_in[2];
  const float* maa_wa = (const float*)d_in[3];
  const float* maa_k = (const float*)d_in[4];
  const float* maa_v = (const float*)d_in[5];
  const float* maa_w1 = (const float*)d_in[6];
  const float* maa_w2 = (const float*)d_in[7];
  const float* tdecay = (const float*)d_in[8];
  const float* dec_w1 = (const float*)d_in[9];
  const float* dec_w2 = (const float*)d_in[10];
  const float* faaaa = (const float*)d_in[11];
  const float* aaaaa = (const float*)d_in[12];
  const float* aaa_w1 = (const float*)d_in[13];
  const float* aaa_w2 = (const float*)d_in[14];
  const float* kkk_w1 = (const float*)d_in[15];
  const float* kkk_w2 = (const float*)d_in[16];
  const float* gate_w1 = (const float*)d_in[17];
  const float* gate_w2 = (const float*)d_in[18];
  const float* ma_w1 = (const float*)d_in[19];
  const float* ma_w2 = (const float*)d_in[20];
  const float* misc_a = (const float*)d_in[21];
  const float* mk_w1 = (const float*)d_in[22];
  const float* mk_w2 = (const float*)d_in[23];
  const float* misc_k = (const float*)d_in[24];
  const float* w_r = (const float*)d_in[25];
  const float* w_k = (const float*)d_in[26];
  const float* w_v = (const float*)d_in[27];
  const float* w_o = (const float*)d_in[28];
  const float* lnw = (const float*)d_in[29];
  const float* lnb = (const float*)d_in[30];
  float* out = (float*)d_out;

  float* ws = (float*)d_ws;
  const size_t F = (size_t)BT * Cdim;  // 4M elements
  float* rb = ws + 0 * F;
  float* kb = ws + 1 * F;
  float* vb = ws + 2 * F;
  float* kkb = ws + 3 * F;
  float* ab = ws + 4 * F;
  float* wexpb = ws + 5 * F;
  float* yb = ws + 6 * F;
  float* gup = ws + 7 * F;
  float* sm = ws + 8 * F;
  float* mixin_raw = sm;                         // BT*128
  float* g_raw = mixin_raw + (size_t)BT * 128;   // BT*128
  float* wa_mid = g_raw + (size_t)BT * 128;      // BT*128
  float* k_mid = wa_mid + (size_t)BT * 128;      // BT*64

  ushort_t* ub = (ushort_t*)(k_mid + (size_t)BT * 64);
  ushort_t* xmix_bf = ub + 0 * F;
  ushort_t* xrg_bf = ub + 1 * F;
  ushort_t* xwa_bf = ub + 2 * F;
  ushort_t* xk_bf = ub + 3 * F;
  ushort_t* xv_bf = ub + 4 * F;
  ushort_t* yg_bf = ub + 5 * F;
  ushort_t* wr_bf = ub + 6 * F;
  ushort_t* wk_bf = wr_bf + (size_t)Cdim * Cdim;
  ushort_t* wv_bf = wk_bf + (size_t)Cdim * Cdim;
  ushort_t* wo_bf = wv_bf + (size_t)Cdim * Cdim;
  ushort_t* Tmaa = wo_bf + (size_t)Cdim * Cdim;   // 128*1024
  ushort_t* Tgate = Tmaa + 128 * 1024;            // 128*1024
  ushort_t* Twa = Tgate + 128 * 1024;             // 128*1024
  ushort_t* Tk = Twa + 128 * 1024;                // 64*1024

  dim3 blk(256);
  dim3 g1024(BT / 128, 16);
  dim3 g128(BT / 128, 2);
  dim3 g64(BT / 128, 1);

  // 0. weight prep
  k_f2bf4<<<4096, blk, 0, stream>>>(w_r, w_k, w_v, w_o, wr_bf, wk_bf, wv_bf, wo_bf);
  k_prepw<<<dim3(16, 7), blk, 0, stream>>>(maa_w1, gate_w1, dec_w1, aaa_w1, ma_w1,
                                           kkk_w1, mk_w1, Tmaa, Tgate, Twa, Tk);
  // 1. xmix -> bf16
  k_xmix<<<(BT * Cdim) / 256, blk, 0, stream>>>(x, maa_x, xmix_bf);
  // 2. mixin_raw = xmix @ maa_w1 (tanh deferred to mixup)
  k_gemm_mfma<<<g128, blk, 0, stream>>>(xmix_bf, Tmaa, mixin_raw, BT, 128, Cdim);
  // 3. mix-up -> 4 bf16 planes
  k_mixup<<<BT / 8, blk, 0, stream>>>(x, mixin_raw, maa_w2, maa_rg, maa_wa, maa_k,
                                      maa_v, xrg_bf, xwa_bf, xk_bf, xv_bf);
  // 4-9. GEMMs
  k_gemm_mfma<<<g1024, blk, 0, stream>>>(xrg_bf, wr_bf, rb, BT, Cdim, Cdim);
  k_gemm_mfma<<<g1024, blk, 0, stream>>>(xk_bf, wk_bf, kb, BT, Cdim, Cdim);
  k_gemm_mfma<<<g1024, blk, 0, stream>>>(xv_bf, wv_bf, vb, BT, Cdim, Cdim);
  k_gemm_mfma<<<g128, blk, 0, stream>>>(xrg_bf, Tgate, g_raw, BT, 128, Cdim);
  k_gemm_mfma<<<g128, blk, 0, stream>>>(xwa_bf, Twa, wa_mid, BT, 128, Cdim);
  k_gemm_mfma<<<g64, blk, 0, stream>>>(xk_bf, Tk, k_mid, BT, 64, Cdim);
  // 10. gate up (tanh on load)
  k_up<128><<<BT / 8, blk, 0, stream>>>(g_raw, gate_w2, gup);
  // 11. combine v2
  k_combine<<<dim3(4, BT / 16), blk, 0, stream>>>(
      kb, wa_mid, k_mid, dec_w2, aaa_w2, ma_w2, kkk_w2, mk_w2,
      tdecay, aaaaa, misc_a, misc_k, kkb, ab, wexpb);
  // 12. scan v4
  k_scan<<<256, dim3(64), 0, stream>>>(rb, wexpb, kb, kkb, ab, vb, yb);
  // 13. GN + bonus + gate
  k_gnout<<<BT * 4, blk, 0, stream>>>(yb, rb, kb, vb, gup, faaaa, lnw, lnb, yg_bf);
  // 14. output GEMM
  k_gemm_mfma<<<g1024, blk, 0, stream>>>(yg_bf, wo_bf, out, BT, Cdim, Cdim);
}

// Round 7
// 596.905 us; speedup vs baseline: 2.9764x; 1.6107x over previous
//
#include <hip/hip_runtime.h>
#include <math.h>

#define BT   4096
#define Cdim 1024
#define Hn   16
#define Tn   1024

typedef unsigned short ushort_t;
typedef short bf16x8 __attribute__((ext_vector_type(8)));
typedef float f32x4 __attribute__((ext_vector_type(4)));

static __device__ __forceinline__ float sigmoidf_(float z) { return 1.f / (1.f + expf(-z)); }

static __device__ __forceinline__ ushort_t f2bf(float f) {  // RNE fp32->bf16
  unsigned int u = __float_as_uint(f);
  u += 0x7fffu + ((u >> 16) & 1u);
  return (ushort_t)(u >> 16);
}

static __device__ __forceinline__ void gl_lds16(const ushort_t* g, ushort_t* l) {
  __builtin_amdgcn_global_load_lds(
      (const __attribute__((address_space(1))) unsigned int*)g,
      (__attribute__((address_space(3))) unsigned int*)l, 16, 0, 0);
}

// DPP cross-lane add. 0xB1=xor1(quad), 0x4E=xor2(quad), 0x141=ROW_HALF_MIRROR(xor7)
template <int CTRL>
static __device__ __forceinline__ float dppadd(float x) {
  int t = __builtin_amdgcn_mov_dpp(__float_as_int(x), CTRL, 0xF, 0xF, true);
  return x + __int_as_float(t);
}

// ---------------- fp32 -> bf16: 4 big weight matrices ----------------
__global__ __launch_bounds__(256) void k_f2bf4(
    const float* __restrict__ w0, const float* __restrict__ w1,
    const float* __restrict__ w2, const float* __restrict__ w3,
    ushort_t* __restrict__ o0, ushort_t* __restrict__ o1,
    ushort_t* __restrict__ o2, ushort_t* __restrict__ o3) {
  int idx4 = blockIdx.x * 256 + threadIdx.x;
  int which = idx4 >> 18;
  int loc = (idx4 & 0x3FFFF) * 4;
  const float* in = which == 0 ? w0 : which == 1 ? w1 : which == 2 ? w2 : w3;
  ushort_t* out = which == 0 ? o0 : which == 1 ? o1 : which == 2 ? o2 : o3;
  float4 v = *reinterpret_cast<const float4*>(in + loc);
  ushort4 o;
  o.x = f2bf(v.x); o.y = f2bf(v.y); o.z = f2bf(v.z); o.w = f2bf(v.w);
  *reinterpret_cast<ushort4*>(out + loc) = o;
}

// ---------------- prep: transposed bf16 weight panels (n,k layout for GEMM B) --------
__global__ __launch_bounds__(256) void k_prepw(
    const float* __restrict__ maa_w1, const float* __restrict__ gate_w1,
    const float* __restrict__ dec_w1, const float* __restrict__ aaa_w1,
    const float* __restrict__ ma_w1, const float* __restrict__ kkk_w1,
    const float* __restrict__ mk_w1,
    ushort_t* __restrict__ Tmaa, ushort_t* __restrict__ Tgate,
    ushort_t* __restrict__ Twa, ushort_t* __restrict__ Tk) {
  __shared__ float tile[64][65];
  const int k0 = blockIdx.x * 64, n0 = blockIdx.y * 64;
  for (int i = threadIdx.x; i < 64 * 64; i += 256) {
    int kk_ = i >> 6, nn = i & 63;
    int k = k0 + kk_, n = n0 + nn;
    float v = 0.f;
    if (n < 128) v = maa_w1[k * 128 + n];
    else if (n < 256) v = gate_w1[k * 128 + (n - 128)];
    else if (n < 384) {
      int m = n - 256;
      if (m < 64) v = dec_w1[k * 64 + m];
      else if (m < 80) v = aaa_w1[k * 16 + m - 64];
      else if (m < 96) v = ma_w1[k * 16 + m - 80];
    } else {
      int m = n - 384;
      if (m < 16) v = kkk_w1[k * 16 + m];
      else if (m < 32) v = mk_w1[k * 16 + m - 16];
    }
    tile[kk_][nn] = v;
  }
  __syncthreads();
  for (int i = threadIdx.x; i < 64 * 64; i += 256) {
    int nn = i >> 6, kk_ = i & 63;
    int n = n0 + nn, k = k0 + kk_;
    ushort_t bv = f2bf(tile[kk_][nn]);
    if (n < 128) Tmaa[n * 1024 + k] = bv;
    else if (n < 256) Tgate[(n - 128) * 1024 + k] = bv;
    else if (n < 384) Twa[(n - 256) * 1024 + k] = bv;
    else Tk[(n - 384) * 1024 + k] = bv;
  }
}

// ---------------- prep2: gate_w2 (128 x 1024) -> Tg2[n=1024][k=128] bf16 -------------
__global__ __launch_bounds__(256) void k_prepw2(const float* __restrict__ w2,
                                                ushort_t* __restrict__ Tg2) {
  __shared__ float tile[64][65];
  const int k0 = blockIdx.x * 64, n0 = blockIdx.y * 64;
  for (int i = threadIdx.x; i < 64 * 64; i += 256) {
    int kk_ = i >> 6, nn = i & 63;
    tile[kk_][nn] = w2[(k0 + kk_) * 1024 + n0 + nn];
  }
  __syncthreads();
  for (int i = threadIdx.x; i < 64 * 64; i += 256) {
    int nn = i >> 6, kk_ = i & 63;
    Tg2[(size_t)(n0 + nn) * 128 + k0 + kk_] = f2bf(tile[kk_][nn]);
  }
}

// ---------------- tanh + bf16 convert (gate mid) ----------------
__global__ __launch_bounds__(256) void k_tanhbf(const float* __restrict__ in,
                                                ushort_t* __restrict__ out) {
  int i = (blockIdx.x * 256 + threadIdx.x) * 4;
  float4 v = *reinterpret_cast<const float4*>(in + i);
  ushort4 o;
  o.x = f2bf(tanhf(v.x)); o.y = f2bf(tanhf(v.y));
  o.z = f2bf(tanhf(v.z)); o.w = f2bf(tanhf(v.w));
  *reinterpret_cast<ushort4*>(out + i) = o;
}

// ---------------- xmix -> bf16 ----------------
__global__ __launch_bounds__(256) void k_xmix(const float* __restrict__ x,
                                              const float* __restrict__ maa_x,
                                              ushort_t* __restrict__ out_bf) {
  int idx = blockIdx.x * 256 + threadIdx.x;
  int c = idx & (Cdim - 1);
  int bt = idx >> 10;
  float xv = x[idx];
  float xp = ((bt & (Tn - 1)) == 0) ? 0.f : x[idx - Cdim];
  out_bf[idx] = f2bf(xv + (xp - xv) * maa_x[c]);
}

// ---------------- mix-up: tanh(mixin_raw) lora -> 4 bf16 planes ----------------
__global__ __launch_bounds__(256) void k_mixup(
    const float* __restrict__ x, const float* __restrict__ mixin_raw,
    const float* __restrict__ w2,
    const float* __restrict__ brg_w, const float* __restrict__ bwa_w,
    const float* __restrict__ bk_w, const float* __restrict__ bv_w,
    ushort_t* __restrict__ xrg_bf, ushort_t* __restrict__ xwa_bf,
    ushort_t* __restrict__ xk_bf, ushort_t* __restrict__ xv_bf) {
  constexpr int R = 8;
  __shared__ float smix[R][128];
  const int m0 = blockIdx.x * R;
  for (int idx = threadIdx.x; idx < R * 128; idx += 256)
    smix[idx >> 7][idx & 127] =
        tanhf(mixin_raw[(size_t)(m0 + (idx >> 7)) * 128 + (idx & 127)]);
  __syncthreads();
  for (int cc = 0; cc < 4; ++cc) {
    const int c = cc * 256 + threadIdx.x;
    float acc0[R] = {}, acc1[R] = {}, acc2[R] = {}, acc3[R] = {};
    for (int d = 0; d < 32; ++d) {
      float w0 = w2[(0 * 32 + d) * Cdim + c];
      float w1 = w2[(1 * 32 + d) * Cdim + c];
      float w2v = w2[(2 * 32 + d) * Cdim + c];
      float w3 = w2[(3 * 32 + d) * Cdim + c];
#pragma unroll
      for (int mi = 0; mi < R; ++mi) {
        acc0[mi] += smix[mi][d] * w0;
        acc1[mi] += smix[mi][32 + d] * w1;
        acc2[mi] += smix[mi][64 + d] * w2v;
        acc3[mi] += smix[mi][96 + d] * w3;
      }
    }
    float brg = brg_w[c], bwa = bwa_w[c], bk = bk_w[c], bv = bv_w[c];
#pragma unroll
    for (int mi = 0; mi < R; ++mi) {
      int m = m0 + mi;
      size_t id = (size_t)m * Cdim + c;
      float xvv = x[id];
      float xp = ((m & (Tn - 1)) == 0) ? 0.f : x[id - Cdim];
      float xx = xp - xvv;
      xrg_bf[id] = f2bf(xvv + xx * (brg + acc0[mi]));
      xwa_bf[id] = f2bf(xvv + xx * (bwa + acc1[mi]));
      xk_bf[id] = f2bf(xvv + xx * (bk + acc2[mi]));
      xv_bf[id] = f2bf(xvv + xx * (bv + acc3[mi]));
    }
  }
}

// ---------------- bf16 MFMA GEMM: C[m,n] = sum_k A[m,k]*Bw[n,k]; 128x64 tile ----------
__global__ __launch_bounds__(256) void k_gemm_mfma(
    const ushort_t* __restrict__ A, const ushort_t* __restrict__ Bw,
    float* __restrict__ C, int M, int Ncols, int K) {
  __shared__ ushort_t sh[24576];
  const int tid = threadIdx.x;
  const int lane = tid & 63;
  const int wave = tid >> 6;
  const int wr = wave >> 1, wc = wave & 1;
  const int m0 = blockIdx.x * 128, n0 = blockIdx.y * 64;
  const int NT = K >> 6;
  const ushort_t* gA = A + (size_t)m0 * K;
  const ushort_t* gB = Bw + (size_t)n0 * K;
  const int srow = lane >> 3;
  const int kbs = (lane & 7) ^ (srow & 7);

  f32x4 acc[4][2];
#pragma unroll
  for (int m = 0; m < 4; ++m)
#pragma unroll
    for (int n = 0; n < 2; ++n) acc[m][n] = (f32x4){0.f, 0.f, 0.f, 0.f};

  auto stage = [&](int buf, int k0) {
    ushort_t* LA = sh + buf * 12288;
    ushort_t* LB = LA + 8192;
#pragma unroll
    for (int q = 0; q < 4; ++q) {
      int row = wave * 32 + q * 8 + srow;
      gl_lds16(gA + (size_t)row * K + k0 + kbs * 8, LA + (wave * 4 + q) * 512);
    }
#pragma unroll
    for (int q = 0; q < 2; ++q) {
      int row = wave * 16 + q * 8 + srow;
      gl_lds16(gB + (size_t)row * K + k0 + kbs * 8, LB + (wave * 2 + q) * 512);
    }
  };

  auto compute = [&](int buf) {
    const ushort_t* LA = sh + buf * 12288;
    const ushort_t* LB = LA + 8192;
    const int r15 = lane & 15;
    const int kq = lane >> 4;
    const int rx = lane & 7;
#pragma unroll
    for (int kh = 0; kh < 2; ++kh) {
      bf16x8 af[4], bfr[2];
      const int kbsw = ((kh * 4 + kq) ^ rx) << 3;
#pragma unroll
      for (int m = 0; m < 4; ++m) {
        int row = wr * 64 + m * 16 + r15;
        af[m] = *reinterpret_cast<const bf16x8*>(&LA[row * 64 + kbsw]);
      }
#pragma unroll
      for (int n = 0; n < 2; ++n) {
        int col = wc * 32 + n * 16 + r15;
        bfr[n] = *reinterpret_cast<const bf16x8*>(&LB[col * 64 + kbsw]);
      }
#pragma unroll
      for (int m = 0; m < 4; ++m)
#pragma unroll
        for (int n = 0; n < 2; ++n)
          acc[m][n] = __builtin_amdgcn_mfma_f32_16x16x32_bf16(af[m], bfr[n], acc[m][n], 0, 0, 0);
    }
  };

  stage(0, 0);
  __syncthreads();
  for (int t = 0; t < NT; ++t) {
    int cur = t & 1;
    if (t + 1 < NT) stage(cur ^ 1, (t + 1) << 6);
    compute(cur);
    __syncthreads();
  }

  const int r15 = lane & 15, rq = lane >> 4;
#pragma unroll
  for (int m = 0; m < 4; ++m) {
    int row = m0 + wr * 64 + m * 16 + rq * 4;
#pragma unroll
    for (int n = 0; n < 2; ++n) {
      int col = n0 + wc * 32 + n * 16 + r15;
#pragma unroll
      for (int j = 0; j < 4; ++j)
        C[(size_t)(row + j) * Ncols + col] = acc[m][n][j];
    }
  }
}

// ---------------- combine v2: 5 LoRA-ups + kk-norm + k-mod + scan precompute ----------
__global__ __launch_bounds__(256) void k_combine(
    float* __restrict__ kbuf,
    const float* __restrict__ wa_mid, const float* __restrict__ k_mid,
    const float* __restrict__ dec_w2, const float* __restrict__ aaa_w2,
    const float* __restrict__ ma_w2, const float* __restrict__ kkk_w2,
    const float* __restrict__ mk_w2,
    const float* __restrict__ tdecay, const float* __restrict__ aaaaa,
    const float* __restrict__ misc_a, const float* __restrict__ misc_k,
    float* __restrict__ kkout, float* __restrict__ bout,
    float* __restrict__ wexp) {
  __shared__ float mid[16][128];
  const int hg = blockIdx.x;
  const int bt0 = blockIdx.y * 16;
  const int tid = threadIdx.x;
  const int lane = tid & 63;
  const int btw = (tid >> 6) * 4;
  for (int i = tid; i < 16 * 128; i += 256) {
    int row = i >> 7, col = i & 127;
    float v;
    if (col < 96) v = wa_mid[(size_t)(bt0 + row) * 128 + col];
    else v = k_mid[(size_t)(bt0 + row) * 64 + (col - 96)];
    if (col < 64 || (col >= 96 && col < 112)) v = tanhf(v);
    mid[row][col] = v;
  }
  __syncthreads();

  int cq[4];
#pragma unroll
  for (int q = 0; q < 4; ++q) cq[q] = ((hg * 4 + q) << 6) + lane;

  float acc0[4][4] = {}, acc1[4][4] = {}, acc2[4][4] = {}, acc3[4][4] = {}, acc4[4][4] = {};

#define PASS(ACC, W2P, DBASE, NCH)                                        \
  _Pragma("unroll") for (int ch = 0; ch < NCH; ++ch) {                    \
    const int d0 = ch * 4;                                                \
    float4 m0 = *reinterpret_cast<const float4*>(&mid[btw + 0][DBASE + d0]); \
    float4 m1 = *reinterpret_cast<const float4*>(&mid[btw + 1][DBASE + d0]); \
    float4 m2 = *reinterpret_cast<const float4*>(&mid[btw + 2][DBASE + d0]); \
    float4 m3 = *reinterpret_cast<const float4*>(&mid[btw + 3][DBASE + d0]); \
    _Pragma("unroll") for (int q = 0; q < 4; ++q) {                       \
      const float w0 = W2P[(d0 + 0) * Cdim + cq[q]];                      \
      const float w1 = W2P[(d0 + 1) * Cdim + cq[q]];                      \
      const float w2v = W2P[(d0 + 2) * Cdim + cq[q]];                     \
      const float w3 = W2P[(d0 + 3) * Cdim + cq[q]];                      \
      ACC[0][q] += m0.x * w0 + m0.y * w1 + m0.z * w2v + m0.w * w3;        \
      ACC[1][q] += m1.x * w0 + m1.y * w1 + m1.z * w2v + m1.w * w3;        \
      ACC[2][q] += m2.x * w0 + m2.y * w1 + m2.z * w2v + m2.w * w3;        \
      ACC[3][q] += m3.x * w0 + m3.y * w1 + m3.z * w2v + m3.w * w3;        \
    }                                                                     \
  }

  PASS(acc0, dec_w2, 0, 16)
  PASS(acc1, aaa_w2, 64, 4)
  PASS(acc2, ma_w2, 80, 4)
  PASS(acc3, kkk_w2, 96, 4)
  PASS(acc4, mk_w2, 112, 4)
#undef PASS

#pragma unroll
  for (int bt = 0; bt < 4; ++bt) {
#pragma unroll
    for (int q = 0; q < 4; ++q) {
      const int c = cq[q];
      const size_t idx = (size_t)(bt0 + btw + bt) * Cdim + c;
      float kval = kbuf[idx];
      float kkraw = kval + acc3[bt][q];
      float ss = kkraw * kkraw;
#pragma unroll
      for (int off = 32; off; off >>= 1) ss += __shfl_xor(ss, off, 64);
      float kkn = kkraw / fmaxf(sqrtf(ss), 1e-12f);
      float av = sigmoidf_(aaaaa[c] + acc1[bt][q]);
      float mav = sigmoidf_(misc_a[c] + acc2[bt][q]);
      float mkv = sigmoidf_(misc_k[c] + acc4[bt][q]);
      float z = tdecay[c] + acc0[bt][q];
      float wv = -log1pf(expf(-z)) - 0.5f;
      float kn = (kval * mav + kval * av * (1.f - mav)) * expf(fminf(wv * mkv, 0.f));
      kbuf[idx] = kn;
      kkout[idx] = kkn;
      bout[idx] = kkn * av;
      wexp[idx] = expf(wv);
    }
  }
}

// ---------------- wkv7 scan v6: overlapped chunks (warmup truncation) ----------------
// ||M_t|| <= max(d)+||kk||*||kk*a|| ~ 0.78 => 64-step warmup error ~1e-6 << 2.6e-3.
// Grid 1024 = bh(64) x chunk(8) x half(2). 64 thr (1 wave, no barriers needed).
// Chunk p: steps [p*128-64, p*128+128) (p=0: [0,128)); y written from p*128.
// Lane: jc=lane&7 (8-wide j), rs=lane>>3; rows i0+{0,8,16,24}, i0=half*32+rs.
// 8-step LDS tiles (24 KiB) double-buffered; single-wave => lgkmcnt ordering only.
__global__ __launch_bounds__(64) void k_scan(
    const float* __restrict__ r, const float* __restrict__ wexp,
    const float* __restrict__ k, const float* __restrict__ kk,
    const float* __restrict__ bb, const float* __restrict__ v,
    float* __restrict__ y) {
  __shared__ float lds[2][6][8][64];  // 24 KiB
  const int half = blockIdx.x & 1;
  const int p = (blockIdx.x >> 1) & 7;
  const int bh = blockIdx.x >> 4;
  const int b = bh >> 4, h = bh & 15;
  const int lane = threadIdx.x;
  const int jc = lane & 7, j0 = jc * 8;
  const int rs = lane >> 3;
  const int i0 = half * 32 + rs;
  const size_t sb = (size_t)b * Tn * Cdim + h * 64;
  const int tstart = (p == 0) ? 0 : (p * 128 - 64);
  const int ntile = (p == 0) ? 16 : 24;
  const int wtile = (p == 0) ? 0 : 8;

  float st[4][8] = {};
  float4 g[6][2];
  const float* P0 = r; const float* P1 = wexp; const float* P2 = k;
  const float* P3 = kk; const float* P4 = bb; const float* P5 = v;

#define LOADT(CT) { int bt_ = tstart + (CT) * 8;                          \
    _Pragma("unroll") for (int rep = 0; rep < 2; ++rep) {                 \
      int flat = rep * 64 + lane;                                         \
      int step = flat >> 4; int j4 = (flat & 15) * 4;                     \
      size_t o = sb + (size_t)(bt_ + step) * Cdim + j4;                   \
      g[0][rep] = *reinterpret_cast<const float4*>(P0 + o);               \
      g[1][rep] = *reinterpret_cast<const float4*>(P1 + o);               \
      g[2][rep] = *reinterpret_cast<const float4*>(P2 + o);               \
      g[3][rep] = *reinterpret_cast<const float4*>(P3 + o);               \
      g[4][rep] = *reinterpret_cast<const float4*>(P4 + o);               \
      g[5][rep] = *reinterpret_cast<const float4*>(P5 + o);               \
    } }
#define WRITET(BI) {                                                      \
    _Pragma("unroll") for (int rep = 0; rep < 2; ++rep) {                 \
      int flat = rep * 64 + lane;                                         \
      int step = flat >> 4; int j4 = (flat & 15) * 4;                     \
      _Pragma("unroll") for (int a_ = 0; a_ < 6; ++a_)                    \
        *reinterpret_cast<float4*>(&lds[BI][a_][step][j4]) = g[a_][rep];  \
    } }

  LOADT(0);
  WRITET(0);

  for (int c = 0; c < ntile; ++c) {
    const int cur = c & 1;
    if (c + 1 < ntile) LOADT(c + 1);
    const float(*Lc)[8][64] = lds[cur];
    const bool wr = (c >= wtile) && (jc == 0);
    const int gt0 = tstart + c * 8;
#pragma unroll
    for (int s_ = 0; s_ < 8; ++s_) {
      const float4 R0 = *reinterpret_cast<const float4*>(&Lc[0][s_][j0]);
      const float4 R1 = *reinterpret_cast<const float4*>(&Lc[0][s_][j0 + 4]);
      const float4 W0 = *reinterpret_cast<const float4*>(&Lc[1][s_][j0]);
      const float4 W1 = *reinterpret_cast<const float4*>(&Lc[1][s_][j0 + 4]);
      const float4 K0 = *reinterpret_cast<const float4*>(&Lc[2][s_][j0]);
      const float4 K1 = *reinterpret_cast<const float4*>(&Lc[2][s_][j0 + 4]);
      const float4 A0 = *reinterpret_cast<const float4*>(&Lc[3][s_][j0]);
      const float4 A1 = *reinterpret_cast<const float4*>(&Lc[3][s_][j0 + 4]);
      const float4 B0 = *reinterpret_cast<const float4*>(&Lc[4][s_][j0]);
      const float4 B1 = *reinterpret_cast<const float4*>(&Lc[4][s_][j0 + 4]);
      float vv[4], pr[4], yr[4];
#pragma unroll
      for (int m = 0; m < 4; ++m) vv[m] = Lc[5][s_][i0 + 8 * m];
#pragma unroll
      for (int m = 0; m < 4; ++m) {
        pr[m] = st[m][0] * A0.x + st[m][1] * A0.y + st[m][2] * A0.z + st[m][3] * A0.w
              + st[m][4] * A1.x + st[m][5] * A1.y + st[m][6] * A1.z + st[m][7] * A1.w;
      }
#pragma unroll
      for (int m = 0; m < 4; ++m) pr[m] = dppadd<0xB1>(pr[m]);
#pragma unroll
      for (int m = 0; m < 4; ++m) pr[m] = dppadd<0x4E>(pr[m]);
#pragma unroll
      for (int m = 0; m < 4; ++m) pr[m] = dppadd<0x141>(pr[m]);
#pragma unroll
      for (int m = 0; m < 4; ++m) {
        st[m][0] = st[m][0] * W0.x + (vv[m] * K0.x - pr[m] * B0.x);
        st[m][1] = st[m][1] * W0.y + (vv[m] * K0.y - pr[m] * B0.y);
        st[m][2] = st[m][2] * W0.z + (vv[m] * K0.z - pr[m] * B0.z);
        st[m][3] = st[m][3] * W0.w + (vv[m] * K0.w - pr[m] * B0.w);
        st[m][4] = st[m][4] * W1.x + (vv[m] * K1.x - pr[m] * B1.x);
        st[m][5] = st[m][5] * W1.y + (vv[m] * K1.y - pr[m] * B1.y);
        st[m][6] = st[m][6] * W1.z + (vv[m] * K1.z - pr[m] * B1.z);
        st[m][7] = st[m][7] * W1.w + (vv[m] * K1.w - pr[m] * B1.w);
        yr[m] = st[m][0] * R0.x + st[m][1] * R0.y + st[m][2] * R0.z + st[m][3] * R0.w
              + st[m][4] * R1.x + st[m][5] * R1.y + st[m][6] * R1.z + st[m][7] * R1.w;
      }
#pragma unroll
      for (int m = 0; m < 4; ++m) yr[m] = dppadd<0xB1>(yr[m]);
#pragma unroll
      for (int m = 0; m < 4; ++m) yr[m] = dppadd<0x4E>(yr[m]);
#pragma unroll
      for (int m = 0; m < 4; ++m) yr[m] = dppadd<0x141>(yr[m]);
      if (wr) {
        size_t yo = sb + (size_t)(gt0 + s_) * Cdim + i0;
        y[yo] = yr[0];
        y[yo + 8] = yr[1];
        y[yo + 16] = yr[2];
        y[yo + 24] = yr[3];
      }
    }
    if (c + 1 < ntile) WRITET((c + 1) & 1);
  }
#undef LOADT
#undef WRITET
}

// ---------------- GroupNorm + bonus + gate -> bf16 ----------------
__global__ __launch_bounds__(256) void k_gnout(
    const float* __restrict__ y, const float* __restrict__ r,
    const float* __restrict__ k, const float* __restrict__ v,
    const float* __restrict__ g, const float* __restrict__ faaaa,
    const float* __restrict__ lnw, const float* __restrict__ lnb,
    ushort_t* __restrict__ out_bf) {
  const int bt = blockIdx.x >> 2;
  const int h = ((blockIdx.x & 3) << 2) + (threadIdx.x >> 6);
  const int lane = threadIdx.x & 63;
  const int c = h * 64 + lane;
  const size_t idx = (size_t)bt * Cdim + c;
  float yv = y[idx];
  float mu = yv;
#pragma unroll
  for (int off = 32; off; off >>= 1) mu += __shfl_xor(mu, off, 64);
  mu *= (1.f / 64.f);
  float dv = yv - mu;
  float var = dv * dv;
#pragma unroll
  for (int off = 32; off; off >>= 1) var += __shfl_xor(var, off, 64);
  var *= (1.f / 64.f);
  float ynorm = dv * rsqrtf(var + 6.4e-4f) * lnw[c] + lnb[c];
  float rv = r[idx], kv = k[idx], vv = v[idx];
  float psum = rv * kv * faaaa[c];
#pragma unroll
  for (int off = 32; off; off >>= 1) psum += __shfl_xor(psum, off, 64);
  out_bf[idx] = f2bf((ynorm + psum * vv) * g[idx]);
}

extern "C" void kernel_launch(void* const* d_in, const int* in_sizes, int n_in,
                              void* d_out, int out_size, void* d_ws, size_t ws_size,
                              hipStream_t stream) {
  (void)in_sizes; (void)n_in; (void)out_size; (void)ws_size;
  const float* x = (const float*)d_in[0];
  const float* maa_x = (const float*)d_in[1];
  const float* maa_rg = (const float*)d_in[2];
  const float* maa_wa = (const float*)d_in[3];
  const float* maa_k = (const float*)d_in[4];
  const float* maa_v = (const float*)d_in[5];
  const float* maa_w1 = (const float*)d_in[6];
  const float* maa_w2 = (const float*)d_in[7];
  const float* tdecay = (const float*)d_in[8];
  const float* dec_w1 = (const float*)d_in[9];
  const float* dec_w2 = (const float*)d_in[10];
  const float* faaaa = (const float*)d_in[11];
  const float* aaaaa = (const float*)d_in[12];
  const float* aaa_w1 = (const float*)d_in[13];
  const float* aaa_w2 = (const float*)d_in[14];
  const float* kkk_w1 = (const float*)d_in[15];
  const float* kkk_w2 = (const float*)d_in[16];
  const float* gate_w1 = (const float*)d_in[17];
  const float* gate_w2 = (const float*)d_in[18];
  const float* ma_w1 = (const float*)d_in[19];
  const float* ma_w2 = (const float*)d_in[20];
  const float* misc_a = (const float*)d_in[21];
  const float* mk_w1 = (const float*)d_in[22];
  const float* mk_w2 = (const float*)d_in[23];
  const float* misc_k = (const float*)d_in[24];
  const float* w_r = (const float*)d_in[25];
  const float* w_k = (const float*)d_in[26];
  const float* w_v = (const float*)d_in[27];
  const float* w_o = (const float*)d_in[28];
  const float* lnw = (const float*)d_in[29];
  const float* lnb = (const float*)d_in[30];
  float* out = (float*)d_out;

  float* ws = (float*)d_ws;
  const size_t F = (size_t)BT * Cdim;  // 4M elements
  float* rb = ws + 0 * F;
  float* kb = ws + 1 * F;
  float* vb = ws + 2 * F;
  float* kkb = ws + 3 * F;
  float* ab = ws + 4 * F;
  float* wexpb = ws + 5 * F;
  float* yb = ws + 6 * F;
  float* gup = ws + 7 * F;
  float* sm = ws + 8 * F;
  float* mixin_raw = sm;                         // BT*128
  float* g_raw = mixin_raw + (size_t)BT * 128;   // BT*128
  float* wa_mid = g_raw + (size_t)BT * 128;      // BT*128
  float* k_mid = wa_mid + (size_t)BT * 128;      // BT*64

  ushort_t* ub = (ushort_t*)(k_mid + (size_t)BT * 64);
  ushort_t* xmix_bf = ub + 0 * F;
  ushort_t* xrg_bf = ub + 1 * F;
  ushort_t* xwa_bf = ub + 2 * F;
  ushort_t* xk_bf = ub + 3 * F;
  ushort_t* xv_bf = ub + 4 * F;
  ushort_t* yg_bf = ub + 5 * F;
  ushort_t* g_bf = ub + 6 * F;                    // BT*128 bf16 (tanh gate mid)
  ushort_t* wr_bf = g_bf + (size_t)BT * 128;
  ushort_t* wk_bf = wr_bf + (size_t)Cdim * Cdim;
  ushort_t* wv_bf = wk_bf + (size_t)Cdim * Cdim;
  ushort_t* wo_bf = wv_bf + (size_t)Cdim * Cdim;
  ushort_t* Tmaa = wo_bf + (size_t)Cdim * Cdim;   // 128*1024
  ushort_t* Tgate = Tmaa + 128 * 1024;            // 128*1024
  ushort_t* Twa = Tgate + 128 * 1024;             // 128*1024
  ushort_t* Tk = Twa + 128 * 1024;                // 64*1024
  ushort_t* Tg2 = Tk + 64 * 1024;                 // 1024*128

  dim3 blk(256);
  dim3 g1024(BT / 128, 16);
  dim3 g128(BT / 128, 2);
  dim3 g64(BT / 128, 1);

  // 0. weight prep
  k_f2bf4<<<4096, blk, 0, stream>>>(w_r, w_k, w_v, w_o, wr_bf, wk_bf, wv_bf, wo_bf);
  k_prepw<<<dim3(16, 7), blk, 0, stream>>>(maa_w1, gate_w1, dec_w1, aaa_w1, ma_w1,
                                           kkk_w1, mk_w1, Tmaa, Tgate, Twa, Tk);
  k_prepw2<<<dim3(2, 16), blk, 0, stream>>>(gate_w2, Tg2);
  // 1. xmix -> bf16
  k_xmix<<<(BT * Cdim) / 256, blk, 0, stream>>>(x, maa_x, xmix_bf);
  // 2. mixin_raw = xmix @ maa_w1 (tanh deferred to mixup)
  k_gemm_mfma<<<g128, blk, 0, stream>>>(xmix_bf, Tmaa, mixin_raw, BT, 128, Cdim);
  // 3. mix-up -> 4 bf16 planes
  k_mixup<<<BT / 8, blk, 0, stream>>>(x, mixin_raw, maa_w2, maa_rg, maa_wa, maa_k,
                                      maa_v, xrg_bf, xwa_bf, xk_bf, xv_bf);
  // 4-9. GEMMs
  k_gemm_mfma<<<g1024, blk, 0, stream>>>(xrg_bf, wr_bf, rb, BT, Cdim, Cdim);
  k_gemm_mfma<<<g1024, blk, 0, stream>>>(xk_bf, wk_bf, kb, BT, Cdim, Cdim);
  k_gemm_mfma<<<g1024, blk, 0, stream>>>(xv_bf, wv_bf, vb, BT, Cdim, Cdim);
  k_gemm_mfma<<<g128, blk, 0, stream>>>(xrg_bf, Tgate, g_raw, BT, 128, Cdim);
  k_gemm_mfma<<<g128, blk, 0, stream>>>(xwa_bf, Twa, wa_mid, BT, 128, Cdim);
  k_gemm_mfma<<<g64, blk, 0, stream>>>(xk_bf, Tk, k_mid, BT, 64, Cdim);
  // 10. gate mid: tanh -> bf16, then gate-up GEMM (K=128)
  k_tanhbf<<<(BT * 128) / 1024, blk, 0, stream>>>(g_raw, g_bf);
  k_gemm_mfma<<<g1024, blk, 0, stream>>>(g_bf, Tg2, gup, BT, Cdim, 128);
  // 11. combine v2
  k_combine<<<dim3(4, BT / 16), blk, 0, stream>>>(
      kb, wa_mid, k_mid, dec_w2, aaa_w2, ma_w2, kkk_w2, mk_w2,
      tdecay, aaaaa, misc_a, misc_k, kkb, ab, wexpb);
  // 12. scan v6 (overlapped chunks)
  k_scan<<<1024, dim3(64), 0, stream>>>(rb, wexpb, kb, kkb, ab, vb, yb);
  // 13. GN + bonus + gate
  k_gnout<<<BT * 4, blk, 0, stream>>>(yb, rb, kb, vb, gup, faaaa, lnw, lnb, yg_bf);
  // 14. output GEMM
  k_gemm_mfma<<<g1024, blk, 0, stream>>>(yg_bf, wo_bf, out, BT, Cdim, Cdim);
}

// Round 8
// 595.354 us; speedup vs baseline: 2.9842x; 1.0026x over previous
//
#include <hip/hip_runtime.h>
#include <math.h>

#define BT   4096
#define Cdim 1024
#define Hn   16
#define Tn   1024

typedef unsigned short ushort_t;
typedef short bf16x8 __attribute__((ext_vector_type(8)));
typedef float f32x4 __attribute__((ext_vector_type(4)));

static __device__ __forceinline__ float sigmoidf_(float z) { return 1.f / (1.f + expf(-z)); }

static __device__ __forceinline__ ushort_t f2bf(float f) {  // RNE fp32->bf16
  unsigned int u = __float_as_uint(f);
  u += 0x7fffu + ((u >> 16) & 1u);
  return (ushort_t)(u >> 16);
}

static __device__ __forceinline__ void gl_lds16(const ushort_t* g, ushort_t* l) {
  __builtin_amdgcn_global_load_lds(
      (const __attribute__((address_space(1))) unsigned int*)g,
      (__attribute__((address_space(3))) unsigned int*)l, 16, 0, 0);
}

// DPP cross-lane add. 0xB1=xor1(quad), 0x4E=xor2(quad), 0x141=ROW_HALF_MIRROR(xor7)
template <int CTRL>
static __device__ __forceinline__ float dppadd(float x) {
  int t = __builtin_amdgcn_mov_dpp(__float_as_int(x), CTRL, 0xF, 0xF, true);
  return x + __int_as_float(t);
}

// ---------------- fp32 -> bf16: 4 big weight matrices ----------------
__global__ __launch_bounds__(256) void k_f2bf4(
    const float* __restrict__ w0, const float* __restrict__ w1,
    const float* __restrict__ w2, const float* __restrict__ w3,
    ushort_t* __restrict__ o0, ushort_t* __restrict__ o1,
    ushort_t* __restrict__ o2, ushort_t* __restrict__ o3) {
  int idx4 = blockIdx.x * 256 + threadIdx.x;
  int which = idx4 >> 18;
  int loc = (idx4 & 0x3FFFF) * 4;
  const float* in = which == 0 ? w0 : which == 1 ? w1 : which == 2 ? w2 : w3;
  ushort_t* out = which == 0 ? o0 : which == 1 ? o1 : which == 2 ? o2 : o3;
  float4 v = *reinterpret_cast<const float4*>(in + loc);
  ushort4 o;
  o.x = f2bf(v.x); o.y = f2bf(v.y); o.z = f2bf(v.z); o.w = f2bf(v.w);
  *reinterpret_cast<ushort4*>(out + loc) = o;
}

// ---------------- prep: transposed bf16 weight panels ----------------
__global__ __launch_bounds__(256) void k_prepw(
    const float* __restrict__ maa_w1, const float* __restrict__ gate_w1,
    const float* __restrict__ dec_w1, const float* __restrict__ aaa_w1,
    const float* __restrict__ ma_w1, const float* __restrict__ kkk_w1,
    const float* __restrict__ mk_w1,
    ushort_t* __restrict__ Tmaa, ushort_t* __restrict__ Tgate,
    ushort_t* __restrict__ Twa, ushort_t* __restrict__ Tk) {
  __shared__ float tile[64][65];
  const int k0 = blockIdx.x * 64, n0 = blockIdx.y * 64;
  for (int i = threadIdx.x; i < 64 * 64; i += 256) {
    int kk_ = i >> 6, nn = i & 63;
    int k = k0 + kk_, n = n0 + nn;
    float v = 0.f;
    if (n < 128) v = maa_w1[k * 128 + n];
    else if (n < 256) v = gate_w1[k * 128 + (n - 128)];
    else if (n < 384) {
      int m = n - 256;
      if (m < 64) v = dec_w1[k * 64 + m];
      else if (m < 80) v = aaa_w1[k * 16 + m - 64];
      else if (m < 96) v = ma_w1[k * 16 + m - 80];
    } else {
      int m = n - 384;
      if (m < 16) v = kkk_w1[k * 16 + m];
      else if (m < 32) v = mk_w1[k * 16 + m - 16];
    }
    tile[kk_][nn] = v;
  }
  __syncthreads();
  for (int i = threadIdx.x; i < 64 * 64; i += 256) {
    int nn = i >> 6, kk_ = i & 63;
    int n = n0 + nn, k = k0 + kk_;
    ushort_t bv = f2bf(tile[kk_][nn]);
    if (n < 128) Tmaa[n * 1024 + k] = bv;
    else if (n < 256) Tgate[(n - 128) * 1024 + k] = bv;
    else if (n < 384) Twa[(n - 256) * 1024 + k] = bv;
    else Tk[(n - 384) * 1024 + k] = bv;
  }
}

// ---------------- prep2: gate_w2 (128 x 1024) -> Tg2[n=1024][k=128] bf16 -------------
__global__ __launch_bounds__(256) void k_prepw2(const float* __restrict__ w2,
                                                ushort_t* __restrict__ Tg2) {
  __shared__ float tile[64][65];
  const int k0 = blockIdx.x * 64, n0 = blockIdx.y * 64;
  for (int i = threadIdx.x; i < 64 * 64; i += 256) {
    int kk_ = i >> 6, nn = i & 63;
    tile[kk_][nn] = w2[(k0 + kk_) * 1024 + n0 + nn];
  }
  __syncthreads();
  for (int i = threadIdx.x; i < 64 * 64; i += 256) {
    int nn = i >> 6, kk_ = i & 63;
    Tg2[(size_t)(n0 + nn) * 128 + k0 + kk_] = f2bf(tile[kk_][nn]);
  }
}

// ---------------- xmix -> bf16 (x4 vectorized) ----------------
__global__ __launch_bounds__(256) void k_xmix(const float* __restrict__ x,
                                              const float* __restrict__ maa_x,
                                              ushort_t* __restrict__ out_bf) {
  int i4 = (blockIdx.x * 256 + threadIdx.x) * 4;
  int c = i4 & (Cdim - 1);
  int bt = i4 >> 10;
  float4 xv = *reinterpret_cast<const float4*>(x + i4);
  float4 xp = make_float4(0.f, 0.f, 0.f, 0.f);
  if ((bt & (Tn - 1)) != 0) xp = *reinterpret_cast<const float4*>(x + i4 - Cdim);
  float4 mx = *reinterpret_cast<const float4*>(maa_x + c);
  ushort4 o;
  o.x = f2bf(xv.x + (xp.x - xv.x) * mx.x);
  o.y = f2bf(xv.y + (xp.y - xv.y) * mx.y);
  o.z = f2bf(xv.z + (xp.z - xv.z) * mx.z);
  o.w = f2bf(xv.w + (xp.w - xv.w) * mx.w);
  *reinterpret_cast<ushort4*>(out_bf + i4) = o;
}

// ---------------- mix-up: mixin (already tanh'd) lora -> 4 bf16 planes ----------------
__global__ __launch_bounds__(256) void k_mixup(
    const float* __restrict__ x, const float* __restrict__ mixin,
    const float* __restrict__ w2,
    const float* __restrict__ brg_w, const float* __restrict__ bwa_w,
    const float* __restrict__ bk_w, const float* __restrict__ bv_w,
    ushort_t* __restrict__ xrg_bf, ushort_t* __restrict__ xwa_bf,
    ushort_t* __restrict__ xk_bf, ushort_t* __restrict__ xv_bf) {
  constexpr int R = 8;
  __shared__ float smix[R][128];
  const int m0 = blockIdx.x * R;
  for (int idx = threadIdx.x; idx < R * 128; idx += 256)
    smix[idx >> 7][idx & 127] = mixin[(size_t)(m0 + (idx >> 7)) * 128 + (idx & 127)];
  __syncthreads();
  for (int cc = 0; cc < 4; ++cc) {
    const int c = cc * 256 + threadIdx.x;
    float acc0[R] = {}, acc1[R] = {}, acc2[R] = {}, acc3[R] = {};
    for (int d = 0; d < 32; ++d) {
      float w0 = w2[(0 * 32 + d) * Cdim + c];
      float w1 = w2[(1 * 32 + d) * Cdim + c];
      float w2v = w2[(2 * 32 + d) * Cdim + c];
      float w3 = w2[(3 * 32 + d) * Cdim + c];
#pragma unroll
      for (int mi = 0; mi < R; ++mi) {
        acc0[mi] += smix[mi][d] * w0;
        acc1[mi] += smix[mi][32 + d] * w1;
        acc2[mi] += smix[mi][64 + d] * w2v;
        acc3[mi] += smix[mi][96 + d] * w3;
      }
    }
    float brg = brg_w[c], bwa = bwa_w[c], bk = bk_w[c], bv = bv_w[c];
#pragma unroll
    for (int mi = 0; mi < R; ++mi) {
      int m = m0 + mi;
      size_t id = (size_t)m * Cdim + c;
      float xvv = x[id];
      float xp = ((m & (Tn - 1)) == 0) ? 0.f : x[id - Cdim];
      float xx = xp - xvv;
      xrg_bf[id] = f2bf(xvv + xx * (brg + acc0[mi]));
      xwa_bf[id] = f2bf(xvv + xx * (bwa + acc1[mi]));
      xk_bf[id] = f2bf(xvv + xx * (bk + acc2[mi]));
      xv_bf[id] = f2bf(xvv + xx * (bv + acc3[mi]));
    }
  }
}

// ---------------- bf16 MFMA GEMM: 128x64 tile. EPI: 0=f32, 1=tanh f32, 2=tanh bf16 ----
template <int EPI>
__global__ __launch_bounds__(256) void k_gemm_mfma(
    const ushort_t* __restrict__ A, const ushort_t* __restrict__ Bw,
    void* __restrict__ Cv, int M, int Ncols, int K) {
  __shared__ ushort_t sh[24576];
  const int tid = threadIdx.x;
  const int lane = tid & 63;
  const int wave = tid >> 6;
  const int wr = wave >> 1, wc = wave & 1;
  const int m0 = blockIdx.x * 128, n0 = blockIdx.y * 64;
  const int NT = K >> 6;
  const ushort_t* gA = A + (size_t)m0 * K;
  const ushort_t* gB = Bw + (size_t)n0 * K;
  const int srow = lane >> 3;
  const int kbs = (lane & 7) ^ (srow & 7);

  f32x4 acc[4][2];
#pragma unroll
  for (int m = 0; m < 4; ++m)
#pragma unroll
    for (int n = 0; n < 2; ++n) acc[m][n] = (f32x4){0.f, 0.f, 0.f, 0.f};

  auto stage = [&](int buf, int k0) {
    ushort_t* LA = sh + buf * 12288;
    ushort_t* LB = LA + 8192;
#pragma unroll
    for (int q = 0; q < 4; ++q) {
      int row = wave * 32 + q * 8 + srow;
      gl_lds16(gA + (size_t)row * K + k0 + kbs * 8, LA + (wave * 4 + q) * 512);
    }
#pragma unroll
    for (int q = 0; q < 2; ++q) {
      int row = wave * 16 + q * 8 + srow;
      gl_lds16(gB + (size_t)row * K + k0 + kbs * 8, LB + (wave * 2 + q) * 512);
    }
  };

  auto compute = [&](int buf) {
    const ushort_t* LA = sh + buf * 12288;
    const ushort_t* LB = LA + 8192;
    const int r15 = lane & 15;
    const int kq = lane >> 4;
    const int rx = lane & 7;
#pragma unroll
    for (int kh = 0; kh < 2; ++kh) {
      bf16x8 af[4], bfr[2];
      const int kbsw = ((kh * 4 + kq) ^ rx) << 3;
#pragma unroll
      for (int m = 0; m < 4; ++m) {
        int row = wr * 64 + m * 16 + r15;
        af[m] = *reinterpret_cast<const bf16x8*>(&LA[row * 64 + kbsw]);
      }
#pragma unroll
      for (int n = 0; n < 2; ++n) {
        int col = wc * 32 + n * 16 + r15;
        bfr[n] = *reinterpret_cast<const bf16x8*>(&LB[col * 64 + kbsw]);
      }
#pragma unroll
      for (int m = 0; m < 4; ++m)
#pragma unroll
        for (int n = 0; n < 2; ++n)
          acc[m][n] = __builtin_amdgcn_mfma_f32_16x16x32_bf16(af[m], bfr[n], acc[m][n], 0, 0, 0);
    }
  };

  stage(0, 0);
  __syncthreads();
  for (int t = 0; t < NT; ++t) {
    int cur = t & 1;
    if (t + 1 < NT) stage(cur ^ 1, (t + 1) << 6);
    compute(cur);
    __syncthreads();
  }

  const int r15 = lane & 15, rq = lane >> 4;
#pragma unroll
  for (int m = 0; m < 4; ++m) {
    int row = m0 + wr * 64 + m * 16 + rq * 4;
#pragma unroll
    for (int n = 0; n < 2; ++n) {
      int col = n0 + wc * 32 + n * 16 + r15;
#pragma unroll
      for (int j = 0; j < 4; ++j) {
        float val = acc[m][n][j];
        if (EPI == 0) {
          ((float*)Cv)[(size_t)(row + j) * Ncols + col] = val;
        } else if (EPI == 1) {
          ((float*)Cv)[(size_t)(row + j) * Ncols + col] = tanhf(val);
        } else {
          ((ushort_t*)Cv)[(size_t)(row + j) * Ncols + col] = f2bf(tanhf(val));
        }
      }
    }
  }
}

// ---------------- combine v2: 5 LoRA-ups + kk-norm + k-mod + scan precompute ----------
__global__ __launch_bounds__(256) void k_combine(
    float* __restrict__ kbuf,
    const float* __restrict__ wa_mid, const float* __restrict__ k_mid,
    const float* __restrict__ dec_w2, const float* __restrict__ aaa_w2,
    const float* __restrict__ ma_w2, const float* __restrict__ kkk_w2,
    const float* __restrict__ mk_w2,
    const float* __restrict__ tdecay, const float* __restrict__ aaaaa,
    const float* __restrict__ misc_a, const float* __restrict__ misc_k,
    float* __restrict__ kkout, float* __restrict__ bout,
    float* __restrict__ wexp) {
  __shared__ float mid[16][128];
  const int hg = blockIdx.x;
  const int bt0 = blockIdx.y * 16;
  const int tid = threadIdx.x;
  const int lane = tid & 63;
  const int btw = (tid >> 6) * 4;
  for (int i = tid; i < 16 * 128; i += 256) {
    int row = i >> 7, col = i & 127;
    float v;
    if (col < 96) v = wa_mid[(size_t)(bt0 + row) * 128 + col];
    else v = k_mid[(size_t)(bt0 + row) * 64 + (col - 96)];
    if (col < 64 || (col >= 96 && col < 112)) v = tanhf(v);
    mid[row][col] = v;
  }
  __syncthreads();

  int cq[4];
#pragma unroll
  for (int q = 0; q < 4; ++q) cq[q] = ((hg * 4 + q) << 6) + lane;

  float acc0[4][4] = {}, acc1[4][4] = {}, acc2[4][4] = {}, acc3[4][4] = {}, acc4[4][4] = {};

#define PASS(ACC, W2P, DBASE, NCH)                                        \
  _Pragma("unroll") for (int ch = 0; ch < NCH; ++ch) {                    \
    const int d0 = ch * 4;                                                \
    float4 m0 = *reinterpret_cast<const float4*>(&mid[btw + 0][DBASE + d0]); \
    float4 m1 = *reinterpret_cast<const float4*>(&mid[btw + 1][DBASE + d0]); \
    float4 m2 = *reinterpret_cast<const float4*>(&mid[btw + 2][DBASE + d0]); \
    float4 m3 = *reinterpret_cast<const float4*>(&mid[btw + 3][DBASE + d0]); \
    _Pragma("unroll") for (int q = 0; q < 4; ++q) {                       \
      const float w0 = W2P[(d0 + 0) * Cdim + cq[q]];                      \
      const float w1 = W2P[(d0 + 1) * Cdim + cq[q]];                      \
      const float w2v = W2P[(d0 + 2) * Cdim + cq[q]];                     \
      const float w3 = W2P[(d0 + 3) * Cdim + cq[q]];                      \
      ACC[0][q] += m0.x * w0 + m0.y * w1 + m0.z * w2v + m0.w * w3;        \
      ACC[1][q] += m1.x * w0 + m1.y * w1 + m1.z * w2v + m1.w * w3;        \
      ACC[2][q] += m2.x * w0 + m2.y * w1 + m2.z * w2v + m2.w * w3;        \
      ACC[3][q] += m3.x * w0 + m3.y * w1 + m3.z * w2v + m3.w * w3;        \
    }                                                                     \
  }

  PASS(acc0, dec_w2, 0, 16)
  PASS(acc1, aaa_w2, 64, 4)
  PASS(acc2, ma_w2, 80, 4)
  PASS(acc3, kkk_w2, 96, 4)
  PASS(acc4, mk_w2, 112, 4)
#undef PASS

#pragma unroll
  for (int bt = 0; bt < 4; ++bt) {
#pragma unroll
    for (int q = 0; q < 4; ++q) {
      const int c = cq[q];
      const size_t idx = (size_t)(bt0 + btw + bt) * Cdim + c;
      float kval = kbuf[idx];
      float kkraw = kval + acc3[bt][q];
      float ss = kkraw * kkraw;
#pragma unroll
      for (int off = 32; off; off >>= 1) ss += __shfl_xor(ss, off, 64);
      float kkn = kkraw / fmaxf(sqrtf(ss), 1e-12f);
      float av = sigmoidf_(aaaaa[c] + acc1[bt][q]);
      float mav = sigmoidf_(misc_a[c] + acc2[bt][q]);
      float mkv = sigmoidf_(misc_k[c] + acc4[bt][q]);
      float z = tdecay[c] + acc0[bt][q];
      float wv = -log1pf(expf(-z)) - 0.5f;
      float kn = (kval * mav + kval * av * (1.f - mav)) * expf(fminf(wv * mkv, 0.f));
      kbuf[idx] = kn;
      kkout[idx] = kkn;
      bout[idx] = kkn * av;
      wexp[idx] = expf(wv);
    }
  }
}

// ---------------- wkv7 scan v7: overlapped chunks + coalesced y-write ----------------
// Same decomposition as v6 (1024 blocks = bh x chunk(8) x half, 1 wave each, 64-step
// warmup), plus: per-tile y accumulated in LDS ytile[8][32] and flushed cooperatively
// as float4 (8 rows x 128B contiguous) -> kills the 15x HBM write amplification.
__global__ __launch_bounds__(64) void k_scan(
    const float* __restrict__ r, const float* __restrict__ wexp,
    const float* __restrict__ k, const float* __restrict__ kk,
    const float* __restrict__ bb, const float* __restrict__ v,
    float* __restrict__ y) {
  __shared__ float lds[2][6][8][64];  // 24 KiB
  __shared__ float ytile[8][32];      // 1 KiB
  const int half = blockIdx.x & 1;
  const int p = (blockIdx.x >> 1) & 7;
  const int bh = blockIdx.x >> 4;
  const int b = bh >> 4, h = bh & 15;
  const int lane = threadIdx.x;
  const int jc = lane & 7, j0 = jc * 8;
  const int rs = lane >> 3;
  const int i0 = half * 32 + rs;
  const size_t sb = (size_t)b * Tn * Cdim + h * 64;
  const int tstart = (p == 0) ? 0 : (p * 128 - 64);
  const int ntile = (p == 0) ? 16 : 24;
  const int wtile = (p == 0) ? 0 : 8;

  float st[4][8] = {};
  float4 g[6][2];
  const float* P0 = r; const float* P1 = wexp; const float* P2 = k;
  const float* P3 = kk; const float* P4 = bb; const float* P5 = v;

#define LOADT(CT) { int bt_ = tstart + (CT) * 8;                          \
    _Pragma("unroll") for (int rep = 0; rep < 2; ++rep) {                 \
      int flat = rep * 64 + lane;                                         \
      int step = flat >> 4; int j4 = (flat & 15) * 4;                     \
      size_t o = sb + (size_t)(bt_ + step) * Cdim + j4;                   \
      g[0][rep] = *reinterpret_cast<const float4*>(P0 + o);               \
      g[1][rep] = *reinterpret_cast<const float4*>(P1 + o);               \
      g[2][rep] = *reinterpret_cast<const float4*>(P2 + o);               \
      g[3][rep] = *reinterpret_cast<const float4*>(P3 + o);               \
      g[4][rep] = *reinterpret_cast<const float4*>(P4 + o);               \
      g[5][rep] = *reinterpret_cast<const float4*>(P5 + o);               \
    } }
#define WRITET(BI) {                                                      \
    _Pragma("unroll") for (int rep = 0; rep < 2; ++rep) {                 \
      int flat = rep * 64 + lane;                                         \
      int step = flat >> 4; int j4 = (flat & 15) * 4;                     \
      _Pragma("unroll") for (int a_ = 0; a_ < 6; ++a_)                    \
        *reinterpret_cast<float4*>(&lds[BI][a_][step][j4]) = g[a_][rep];  \
    } }

  LOADT(0);
  WRITET(0);

  for (int c = 0; c < ntile; ++c) {
    const int cur = c & 1;
    if (c + 1 < ntile) LOADT(c + 1);
    const float(*Lc)[8][64] = lds[cur];
    const bool live = (c >= wtile);
    const int gt0 = tstart + c * 8;
#pragma unroll
    for (int s_ = 0; s_ < 8; ++s_) {
      const float4 R0 = *reinterpret_cast<const float4*>(&Lc[0][s_][j0]);
      const float4 R1 = *reinterpret_cast<const float4*>(&Lc[0][s_][j0 + 4]);
      const float4 W0 = *reinterpret_cast<const float4*>(&Lc[1][s_][j0]);
      const float4 W1 = *reinterpret_cast<const float4*>(&Lc[1][s_][j0 + 4]);
      const float4 K0 = *reinterpret_cast<const float4*>(&Lc[2][s_][j0]);
      const float4 K1 = *reinterpret_cast<const float4*>(&Lc[2][s_][j0 + 4]);
      const float4 A0 = *reinterpret_cast<const float4*>(&Lc[3][s_][j0]);
      const float4 A1 = *reinterpret_cast<const float4*>(&Lc[3][s_][j0 + 4]);
      const float4 B0 = *reinterpret_cast<const float4*>(&Lc[4][s_][j0]);
      const float4 B1 = *reinterpret_cast<const float4*>(&Lc[4][s_][j0 + 4]);
      float vv[4], pr[4], yr[4];
#pragma unroll
      for (int m = 0; m < 4; ++m) vv[m] = Lc[5][s_][i0 + 8 * m];
#pragma unroll
      for (int m = 0; m < 4; ++m) {
        pr[m] = st[m][0] * A0.x + st[m][1] * A0.y + st[m][2] * A0.z + st[m][3] * A0.w
              + st[m][4] * A1.x + st[m][5] * A1.y + st[m][6] * A1.z + st[m][7] * A1.w;
      }
#pragma unroll
      for (int m = 0; m < 4; ++m) pr[m] = dppadd<0xB1>(pr[m]);
#pragma unroll
      for (int m = 0; m < 4; ++m) pr[m] = dppadd<0x4E>(pr[m]);
#pragma unroll
      for (int m = 0; m < 4; ++m) pr[m] = dppadd<0x141>(pr[m]);
#pragma unroll
      for (int m = 0; m < 4; ++m) {
        st[m][0] = st[m][0] * W0.x + (vv[m] * K0.x - pr[m] * B0.x);
        st[m][1] = st[m][1] * W0.y + (vv[m] * K0.y - pr[m] * B0.y);
        st[m][2] = st[m][2] * W0.z + (vv[m] * K0.z - pr[m] * B0.z);
        st[m][3] = st[m][3] * W0.w + (vv[m] * K0.w - pr[m] * B0.w);
        st[m][4] = st[m][4] * W1.x + (vv[m] * K1.x - pr[m] * B1.x);
        st[m][5] = st[m][5] * W1.y + (vv[m] * K1.y - pr[m] * B1.y);
        st[m][6] = st[m][6] * W1.z + (vv[m] * K1.z - pr[m] * B1.z);
        st[m][7] = st[m][7] * W1.w + (vv[m] * K1.w - pr[m] * B1.w);
        yr[m] = st[m][0] * R0.x + st[m][1] * R0.y + st[m][2] * R0.z + st[m][3] * R0.w
              + st[m][4] * R1.x + st[m][5] * R1.y + st[m][6] * R1.z + st[m][7] * R1.w;
      }
#pragma unroll
      for (int m = 0; m < 4; ++m) yr[m] = dppadd<0xB1>(yr[m]);
#pragma unroll
      for (int m = 0; m < 4; ++m) yr[m] = dppadd<0x4E>(yr[m]);
#pragma unroll
      for (int m = 0; m < 4; ++m) yr[m] = dppadd<0x141>(yr[m]);
      if (live && jc == 0) {
        ytile[s_][rs] = yr[0];
        ytile[s_][rs + 8] = yr[1];
        ytile[s_][rs + 16] = yr[2];
        ytile[s_][rs + 24] = yr[3];
      }
    }
    if (live) {
      // cooperative coalesced flush: 8 steps x 32 ch = 256 floats, 4/lane
      int flat = lane * 4;
      int step = flat >> 5;
      int off = flat & 31;
      float4 yv = *reinterpret_cast<const float4*>(&ytile[step][off]);
      *reinterpret_cast<float4*>(
          &y[sb + (size_t)(gt0 + step) * Cdim + half * 32 + off]) = yv;
      flat += 256;  // second half: lanes cover steps 4..7 v2
      step = flat >> 5;
      off = flat & 31;
      if (step < 8) {
        float4 yv2 = *reinterpret_cast<const float4*>(&ytile[step][off]);
        *reinterpret_cast<float4*>(
            &y[sb + (size_t)(gt0 + step) * Cdim + half * 32 + off]) = yv2;
      }
    }
    if (c + 1 < ntile) WRITET((c + 1) & 1);
  }
#undef LOADT
#undef WRITET
}

// ---------------- GroupNorm + bonus + gate -> bf16 ----------------
__global__ __launch_bounds__(256) void k_gnout(
    const float* __restrict__ y, const float* __restrict__ r,
    const float* __restrict__ k, const float* __restrict__ v,
    const float* __restrict__ g, const float* __restrict__ faaaa,
    const float* __restrict__ lnw, const float* __restrict__ lnb,
    ushort_t* __restrict__ out_bf) {
  const int bt = blockIdx.x >> 2;
  const int h = ((blockIdx.x & 3) << 2) + (threadIdx.x >> 6);
  const int lane = threadIdx.x & 63;
  const int c = h * 64 + lane;
  const size_t idx = (size_t)bt * Cdim + c;
  float yv = y[idx];
  float mu = yv;
#pragma unroll
  for (int off = 32; off; off >>= 1) mu += __shfl_xor(mu, off, 64);
  mu *= (1.f / 64.f);
  float dv = yv - mu;
  float var = dv * dv;
#pragma unroll
  for (int off = 32; off; off >>= 1) var += __shfl_xor(var, off, 64);
  var *= (1.f / 64.f);
  float ynorm = dv * rsqrtf(var + 6.4e-4f) * lnw[c] + lnb[c];
  float rv = r[idx], kv = k[idx], vv = v[idx];
  float psum = rv * kv * faaaa[c];
#pragma unroll
  for (int off = 32; off; off >>= 1) psum += __shfl_xor(psum, off, 64);
  out_bf[idx] = f2bf((ynorm + psum * vv) * g[idx]);
}

extern "C" void kernel_launch(void* const* d_in, const int* in_sizes, int n_in,
                              void* d_out, int out_size, void* d_ws, size_t ws_size,
                              hipStream_t stream) {
  (void)in_sizes; (void)n_in; (void)out_size; (void)ws_size;
  const float* x = (const float*)d_in[0];
  const float* maa_x = (const float*)d_in[1];
  const float* maa_rg = (const float*)d_in[2];
  const float* maa_wa = (const float*)d_in[3];
  const float* maa_k = (const float*)d_in[4];
  const float* maa_v = (const float*)d_in[5];
  const float* maa_w1 = (const float*)d_in[6];
  const float* maa_w2 = (const float*)d_in[7];
  const float* tdecay = (const float*)d_in[8];
  const float* dec_w1 = (const float*)d_in[9];
  const float* dec_w2 = (const float*)d_in[10];
  const float* faaaa = (const float*)d_in[11];
  const float* aaaaa = (const float*)d_in[12];
  const float* aaa_w1 = (const float*)d_in[13];
  const float* aaa_w2 = (const float*)d_in[14];
  const float* kkk_w1 = (const float*)d_in[15];
  const float* kkk_w2 = (const float*)d_in[16];
  const float* gate_w1 = (const float*)d_in[17];
  const float* gate_w2 = (const float*)d_in[18];
  const float* ma_w1 = (const float*)d_in[19];
  const float* ma_w2 = (const float*)d_in[20];
  const float* misc_a = (const float*)d_in[21];
  const float* mk_w1 = (const float*)d_in[22];
  const float* mk_w2 = (const float*)d_in[23];
  const float* misc_k = (const float*)d_in[24];
  const float* w_r = (const float*)d_in[25];
  const float* w_k = (const float*)d_in[26];
  const float* w_v = (const float*)d_in[27];
  const float* w_o = (const float*)d_in[28];
  const float* lnw = (const float*)d_in[29];
  const float* lnb = (const float*)d_in[30];
  float* out = (float*)d_out;

  float* ws = (float*)d_ws;
  const size_t F = (size_t)BT * Cdim;  // 4M elements
  float* rb = ws + 0 * F;
  float* kb = ws + 1 * F;
  float* vb = ws + 2 * F;
  float* kkb = ws + 3 * F;
  float* ab = ws + 4 * F;
  float* wexpb = ws + 5 * F;
  float* yb = ws + 6 * F;
  float* gup = ws + 7 * F;
  float* sm = ws + 8 * F;
  float* mixin = sm;                             // BT*128 (tanh'd, fp32)
  float* wa_mid = mixin + (size_t)BT * 128;      // BT*128
  float* k_mid = wa_mid + (size_t)BT * 128;      // BT*64

  ushort_t* ub = (ushort_t*)(k_mid + (size_t)BT * 64);
  ushort_t* xmix_bf = ub + 0 * F;
  ushort_t* xrg_bf = ub + 1 * F;
  ushort_t* xwa_bf = ub + 2 * F;
  ushort_t* xk_bf = ub + 3 * F;
  ushort_t* xv_bf = ub + 4 * F;
  ushort_t* yg_bf = ub + 5 * F;
  ushort_t* g_bf = ub + 6 * F;                    // BT*128 bf16 (tanh gate mid)
  ushort_t* wr_bf = g_bf + (size_t)BT * 128;
  ushort_t* wk_bf = wr_bf + (size_t)Cdim * Cdim;
  ushort_t* wv_bf = wk_bf + (size_t)Cdim * Cdim;
  ushort_t* wo_bf = wv_bf + (size_t)Cdim * Cdim;
  ushort_t* Tmaa = wo_bf + (size_t)Cdim * Cdim;   // 128*1024
  ushort_t* Tgate = Tmaa + 128 * 1024;            // 128*1024
  ushort_t* Twa = Tgate + 128 * 1024;             // 128*1024
  ushort_t* Tk = Twa + 128 * 1024;                // 64*1024
  ushort_t* Tg2 = Tk + 64 * 1024;                 // 1024*128

  dim3 blk(256);
  dim3 g1024(BT / 128, 16);
  dim3 g128(BT / 128, 2);
  dim3 g64(BT / 128, 1);

  // 0. weight prep
  k_f2bf4<<<4096, blk, 0, stream>>>(w_r, w_k, w_v, w_o, wr_bf, wk_bf, wv_bf, wo_bf);
  k_prepw<<<dim3(16, 7), blk, 0, stream>>>(maa_w1, gate_w1, dec_w1, aaa_w1, ma_w1,
                                           kkk_w1, mk_w1, Tmaa, Tgate, Twa, Tk);
  k_prepw2<<<dim3(2, 16), blk, 0, stream>>>(gate_w2, Tg2);
  // 1. xmix -> bf16
  k_xmix<<<(BT * Cdim) / 1024, blk, 0, stream>>>(x, maa_x, xmix_bf);
  // 2. mixin = tanh(xmix @ maa_w1)  (tanh in GEMM epilogue)
  k_gemm_mfma<1><<<g128, blk, 0, stream>>>(xmix_bf, Tmaa, mixin, BT, 128, Cdim);
  // 3. mix-up -> 4 bf16 planes
  k_mixup<<<BT / 8, blk, 0, stream>>>(x, mixin, maa_w2, maa_rg, maa_wa, maa_k,
                                      maa_v, xrg_bf, xwa_bf, xk_bf, xv_bf);
  // 4-9. GEMMs
  k_gemm_mfma<0><<<g1024, blk, 0, stream>>>(xrg_bf, wr_bf, rb, BT, Cdim, Cdim);
  k_gemm_mfma<0><<<g1024, blk, 0, stream>>>(xk_bf, wk_bf, kb, BT, Cdim, Cdim);
  k_gemm_mfma<0><<<g1024, blk, 0, stream>>>(xv_bf, wv_bf, vb, BT, Cdim, Cdim);
  k_gemm_mfma<2><<<g128, blk, 0, stream>>>(xrg_bf, Tgate, g_bf, BT, 128, Cdim);
  k_gemm_mfma<0><<<g128, blk, 0, stream>>>(xwa_bf, Twa, wa_mid, BT, 128, Cdim);
  k_gemm_mfma<0><<<g64, blk, 0, stream>>>(xk_bf, Tk, k_mid, BT, 64, Cdim);
  // 10. gate-up GEMM (K=128)
  k_gemm_mfma<0><<<g1024, blk, 0, stream>>>(g_bf, Tg2, gup, BT, Cdim, 128);
  // 11. combine v2
  k_combine<<<dim3(4, BT / 16), blk, 0, stream>>>(
      kb, wa_mid, k_mid, dec_w2, aaa_w2, ma_w2, kkk_w2, mk_w2,
      tdecay, aaaaa, misc_a, misc_k, kkb, ab, wexpb);
  // 12. scan v7 (overlapped chunks + coalesced y-write)
  k_scan<<<1024, dim3(64), 0, stream>>>(rb, wexpb, kb, kkb, ab, vb, yb);
  // 13. GN + bonus + gate
  k_gnout<<<BT * 4, blk, 0, stream>>>(yb, rb, kb, vb, gup, faaaa, lnw, lnb, yg_bf);
  // 14. output GEMM
  k_gemm_mfma<0><<<g1024, blk, 0, stream>>>(yg_bf, wo_bf, out, BT, Cdim, Cdim);
}